// Round 1
// baseline (1789.558 us; speedup 1.0000x reference)
//
#include <hip/hip_runtime.h>
#include <math.h>

#define N_NODES 50000
#define N_EDGES 300000
#define IN_DIM 64
#define H 256
#define LAYERS 4
#define NB 181
#define NGRAPH 64
#define EE (N_EDGES + N_NODES)
#define NEG_SLOPE 0.2f
#define LN_EPS 1e-5f

// ---------------- utility ----------------
__device__ __forceinline__ float wave_reduce_sum(float v) {
  #pragma unroll
  for (int off = 32; off > 0; off >>= 1) v += __shfl_xor(v, off, 64);
  return v;
}

// ---------------- CSR build ----------------
__global__ void init_counts_kernel(int* __restrict__ cnt) {
  int i = blockIdx.x * 256 + threadIdx.x;
  if (i < N_NODES) cnt[i] = 1;  // self loop
}

__global__ void count_edges_kernel(const int* __restrict__ dst, int* __restrict__ cnt) {
  int e = blockIdx.x * 256 + threadIdx.x;
  if (e < N_EDGES) atomicAdd(&cnt[dst[e]], 1);
}

__global__ void scan_blocks_kernel(const int* __restrict__ cnt, int* __restrict__ partial,
                                   int* __restrict__ bsums, int n) {
  __shared__ int buf[256];
  int tid = threadIdx.x;
  int i = blockIdx.x * 256 + tid;
  buf[tid] = (i < n) ? cnt[i] : 0;
  __syncthreads();
  #pragma unroll
  for (int off = 1; off < 256; off <<= 1) {
    int t = (tid >= off) ? buf[tid - off] : 0;
    __syncthreads();
    buf[tid] += t;
    __syncthreads();
  }
  if (i < n) partial[i] = buf[tid];
  if (tid == 255) bsums[blockIdx.x] = buf[255];
}

__global__ void scan_sums_kernel(int* __restrict__ bsums, int nblk) {
  __shared__ int buf[256];
  int tid = threadIdx.x;
  buf[tid] = (tid < nblk) ? bsums[tid] : 0;
  __syncthreads();
  #pragma unroll
  for (int off = 1; off < 256; off <<= 1) {
    int t = (tid >= off) ? buf[tid - off] : 0;
    __syncthreads();
    buf[tid] += t;
    __syncthreads();
  }
  if (tid < nblk) bsums[tid] = buf[tid];  // inclusive
}

__global__ void scan_write_kernel(const int* __restrict__ partial, const int* __restrict__ bsums,
                                  int* __restrict__ rowp, int n) {
  int i = blockIdx.x * 256 + threadIdx.x;
  if (i < n) {
    int b = blockIdx.x;
    int off = (b > 0) ? bsums[b - 1] : 0;
    rowp[i + 1] = partial[i] + off;
    if (i == 0) rowp[0] = 0;
  }
}

__global__ void fill_self_kernel(const int* __restrict__ rowp, int* __restrict__ col,
                                 int* __restrict__ fillpos) {
  int i = blockIdx.x * 256 + threadIdx.x;
  if (i < N_NODES) {
    int p = rowp[i];
    col[p] = i;
    fillpos[i] = p + 1;
  }
}

__global__ void fill_edges_kernel(const int* __restrict__ src, const int* __restrict__ dst,
                                  int* __restrict__ fillpos, int* __restrict__ col) {
  int e = blockIdx.x * 256 + threadIdx.x;
  if (e < N_EDGES) {
    int d = dst[e];
    int p = atomicAdd(&fillpos[d], 1);
    col[p] = src[e];
  }
}

// ---------------- GEMM: C[M,Nc] = A[M,K] @ W[Nc,K]^T + bias, opt relu ----------------
#define BM 64
#define BN 64
#define BK 16
#define LDST 72

__global__ __launch_bounds__(256) void gemm_bias_kernel(
    const float* __restrict__ A, const float* __restrict__ W,
    const float* __restrict__ bias, float* __restrict__ C,
    int M, int K, int Nc, int relu)
{
  __shared__ float As[BK][LDST];
  __shared__ float Bs[BK][LDST];
  int tid = threadIdx.x;
  int bm = blockIdx.y * BM;
  int bn = blockIdx.x * BN;
  int tm = (tid >> 4) << 2;
  int tn = (tid & 15) << 2;
  float acc[4][4] = {};
  for (int k0 = 0; k0 < K; k0 += BK) {
    #pragma unroll
    for (int i = 0; i < 4; i++) {
      int idx = tid + i * 256;
      int r  = idx >> 4;
      int kk = idx & 15;
      int gr = bm + r;
      As[kk][r] = (gr < M) ? A[(size_t)gr * K + k0 + kk] : 0.0f;
      Bs[kk][r] = W[(size_t)(bn + r) * K + k0 + kk];
    }
    __syncthreads();
    #pragma unroll
    for (int kk = 0; kk < BK; kk++) {
      float4 a4 = *(const float4*)&As[kk][tm];
      float4 b4 = *(const float4*)&Bs[kk][tn];
      float av[4] = {a4.x, a4.y, a4.z, a4.w};
      float bv[4] = {b4.x, b4.y, b4.z, b4.w};
      #pragma unroll
      for (int i = 0; i < 4; i++)
        #pragma unroll
        for (int j = 0; j < 4; j++)
          acc[i][j] += av[i] * bv[j];
    }
    __syncthreads();
  }
  float4 bias4 = *(const float4*)&bias[bn + tn];
  float bb[4] = {bias4.x, bias4.y, bias4.z, bias4.w};
  #pragma unroll
  for (int i = 0; i < 4; i++) {
    int gr = bm + tm + i;
    if (gr < M) {
      float4 o;
      float t0 = acc[i][0] + bb[0];
      float t1 = acc[i][1] + bb[1];
      float t2 = acc[i][2] + bb[2];
      float t3 = acc[i][3] + bb[3];
      if (relu) { t0 = fmaxf(t0, 0.f); t1 = fmaxf(t1, 0.f); t2 = fmaxf(t2, 0.f); t3 = fmaxf(t3, 0.f); }
      o.x = t0; o.y = t1; o.z = t2; o.w = t3;
      *(float4*)&C[(size_t)gr * Nc + bn + tn] = o;
    }
  }
}

// ---------------- fused edge softmax + aggregate + LN + residual ----------------
__global__ __launch_bounds__(256) void layer_fused_kernel(
    const float* __restrict__ xl, const float* __restrict__ xr,
    float* __restrict__ x,
    const int* __restrict__ rowp, const int* __restrict__ col,
    const float* __restrict__ att, const float* __restrict__ bias_c,
    const float* __restrict__ ln_g, const float* __restrict__ ln_b)
{
  int lane = threadIdx.x & 63;
  int v = blockIdx.x * 4 + (threadIdx.x >> 6);
  if (v >= N_NODES) return;
  int f4 = lane << 2;
  size_t rowbase = (size_t)v * H;
  float4 xrv  = *(const float4*)&xr[rowbase + f4];
  float4 attv = *(const float4*)&att[f4];
  int beg = rowp[v], end = rowp[v + 1];
  float m = -INFINITY, d = 0.0f;
  float4 o = make_float4(0.f, 0.f, 0.f, 0.f);
  for (int p = beg; p < end; p++) {
    int u = col[p];
    float4 a = *(const float4*)&xl[(size_t)u * H + f4];
    float tx = a.x + xrv.x, ty = a.y + xrv.y, tz = a.z + xrv.z, tw = a.w + xrv.w;
    tx = tx > 0.f ? tx : NEG_SLOPE * tx;
    ty = ty > 0.f ? ty : NEG_SLOPE * ty;
    tz = tz > 0.f ? tz : NEG_SLOPE * tz;
    tw = tw > 0.f ? tw : NEG_SLOPE * tw;
    float pe = tx * attv.x + ty * attv.y + tz * attv.z + tw * attv.w;
    pe = wave_reduce_sum(pe);
    float mn  = fmaxf(m, pe);
    float sc  = __expf(m - mn);
    float wgt = __expf(pe - mn);
    d = d * sc + wgt;
    o.x = o.x * sc + wgt * a.x;
    o.y = o.y * sc + wgt * a.y;
    o.z = o.z * sc + wgt * a.z;
    o.w = o.w * sc + wgt * a.w;
    m = mn;
  }
  float invd = 1.0f / d;
  float4 bc4 = *(const float4*)&bias_c[f4];
  float ox = o.x * invd + bc4.x;
  float oy = o.y * invd + bc4.y;
  float oz = o.z * invd + bc4.z;
  float ow = o.w * invd + bc4.w;
  // layernorm over H=256
  float s = wave_reduce_sum(ox + oy + oz + ow);
  float mean = s * (1.0f / H);
  float cx = ox - mean, cy = oy - mean, cz = oz - mean, cw = ow - mean;
  float sq = wave_reduce_sum(cx * cx + cy * cy + cz * cz + cw * cw);
  float rstd = rsqrtf(sq * (1.0f / H) + LN_EPS);
  float4 g4 = *(const float4*)&ln_g[f4];
  float4 b4 = *(const float4*)&ln_b[f4];
  float4 xres = *(const float4*)&x[rowbase + f4];
  float4 y;
  y.x = fmaxf(cx * rstd * g4.x + b4.x, 0.f) + xres.x;
  y.y = fmaxf(cy * rstd * g4.y + b4.y, 0.f) + xres.y;
  y.z = fmaxf(cz * rstd * g4.z + b4.z, 0.f) + xres.z;
  y.w = fmaxf(cw * rstd * g4.w + b4.w, 0.f) + xres.w;
  *(float4*)&x[rowbase + f4] = y;
}

// ---------------- gate scalar: gate[v] = dot(hidden[v], Wg2) + bg2 ----------------
__global__ __launch_bounds__(256) void rowdot_kernel(
    const float* __restrict__ hidden, const float* __restrict__ Wg2,
    const float* __restrict__ bg2, float* __restrict__ gate)
{
  int lane = threadIdx.x & 63;
  int v = blockIdx.x * 4 + (threadIdx.x >> 6);
  if (v >= N_NODES) return;
  int f4 = lane << 2;
  float4 hv = *(const float4*)&hidden[(size_t)v * H + f4];
  float4 wv = *(const float4*)&Wg2[f4];
  float p = hv.x * wv.x + hv.y * wv.y + hv.z * wv.z + hv.w * wv.w;
  p = wave_reduce_sum(p);
  if (lane == 0) gate[v] = p + bg2[0];
}

// ---------------- graph bounds ----------------
__global__ void ginit_kernel(int* __restrict__ gstart, int* __restrict__ gend) {
  int t = threadIdx.x;
  if (t < NGRAPH) { gstart[t] = N_NODES; gend[t] = 0; }
}

__global__ void gbounds_kernel(const int* __restrict__ batch, int* __restrict__ gstart,
                               int* __restrict__ gend) {
  int i = blockIdx.x * 256 + threadIdx.x;
  if (i < N_NODES) {
    int g = batch[i];
    atomicMin(&gstart[g], i);
    atomicMax(&gend[g], i + 1);
  }
}

// ---------------- pooling: softmax over nodes per graph, weighted sum of x ----------------
__global__ __launch_bounds__(256) void pool_kernel(
    const float* __restrict__ gate, const float* __restrict__ x,
    const int* __restrict__ gstart, const int* __restrict__ gend,
    float* __restrict__ pooled)
{
  __shared__ float red[256];
  __shared__ float wl[256];
  int g = blockIdx.x, tid = threadIdx.x;
  int s = gstart[g], e = gend[g];
  float acc = 0.0f;
  if (s < e) {
    float lm = -INFINITY;
    for (int i = s + tid; i < e; i += 256) lm = fmaxf(lm, gate[i]);
    red[tid] = lm;
    __syncthreads();
    for (int off = 128; off; off >>= 1) {
      if (tid < off) red[tid] = fmaxf(red[tid], red[tid + off]);
      __syncthreads();
    }
    float m = red[0];
    __syncthreads();
    float lsum = 0.0f;
    for (int i = s + tid; i < e; i += 256) lsum += __expf(gate[i] - m);
    red[tid] = lsum;
    __syncthreads();
    for (int off = 128; off; off >>= 1) {
      if (tid < off) red[tid] += red[tid + off];
      __syncthreads();
    }
    float invd = 1.0f / red[0];
    __syncthreads();
    for (int s0 = s; s0 < e; s0 += 256) {
      int c = min(256, e - s0);
      wl[tid] = (tid < c) ? __expf(gate[s0 + tid] - m) * invd : 0.0f;
      __syncthreads();
      for (int j = 0; j < c; j++) acc += wl[j] * x[(size_t)(s0 + j) * H + tid];
      __syncthreads();
    }
  }
  pooled[(size_t)g * H + tid] = acc;
}

// ---------------- small GEMM (G rows): C[g,j] = act(A[g]·W[j] + bias[j]) ----------------
__global__ __launch_bounds__(256) void small_gemm_kernel(
    const float* __restrict__ A, const float* __restrict__ W,
    const float* __restrict__ bias, float* __restrict__ C,
    int K, int Nc, int relu)
{
  __shared__ float arow[256];
  int g = blockIdx.x, j = threadIdx.x;
  if (j < K) arow[j] = A[(size_t)g * K + j];
  __syncthreads();
  if (j >= Nc) return;
  float acc = bias[j];
  const float4* wr = (const float4*)&W[(size_t)j * K];
  for (int k4 = 0; k4 < K / 4; k4++) {
    float4 wv = wr[k4];
    float4 av = *(const float4*)&arow[k4 * 4];
    acc += av.x * wv.x + av.y * wv.y + av.z * wv.z + av.w * wv.w;
  }
  if (relu) acc = fmaxf(acc, 0.f);
  C[(size_t)g * Nc + j] = acc;
}

// ---------------- final residual: out[g] = tanh(r1[g]·Wr2 + br2) ----------------
__global__ void residual_kernel(const float* __restrict__ r1, const float* __restrict__ Wr2,
                                const float* __restrict__ br2, float* __restrict__ out) {
  int g = threadIdx.x;
  if (g < NGRAPH) {
    float acc = br2[0];
    for (int k = 0; k < 128; k++) acc += r1[(size_t)g * 128 + k] * Wr2[k];
    out[g] = tanhf(acc);
  }
}

// ---------------- launcher ----------------
extern "C" void kernel_launch(void* const* d_in, const int* in_sizes, int n_in,
                              void* d_out, int out_size, void* d_ws, size_t ws_size,
                              hipStream_t stream) {
  const float* x_in   = (const float*)d_in[0];
  const int*   eidx   = (const int*)d_in[1];
  const int*   batch  = (const int*)d_in[2];
  const float* W_in   = (const float*)d_in[3];
  const float* b_in   = (const float*)d_in[4];
  const float* Wl     = (const float*)d_in[5];
  const float* bl     = (const float*)d_in[6];
  const float* Wr     = (const float*)d_in[7];
  const float* br     = (const float*)d_in[8];
  const float* att    = (const float*)d_in[9];
  const float* bias_c = (const float*)d_in[10];
  const float* ln_g   = (const float*)d_in[11];
  const float* ln_b   = (const float*)d_in[12];
  const float* Wg1    = (const float*)d_in[13];
  const float* bg1    = (const float*)d_in[14];
  const float* Wg2    = (const float*)d_in[15];
  const float* bg2    = (const float*)d_in[16];
  const float* Ws     = (const float*)d_in[17];
  const float* bs     = (const float*)d_in[18];
  const float* Wc     = (const float*)d_in[19];
  const float* bc     = (const float*)d_in[20];
  const float* Wr1    = (const float*)d_in[21];
  const float* br1    = (const float*)d_in[22];
  const float* Wr2    = (const float*)d_in[23];
  const float* br2    = (const float*)d_in[24];
  float* out = (float*)d_out;

  char* w = (char*)d_ws;
  float* x    = (float*)w;  w += sizeof(float) * (size_t)N_NODES * H;
  float* xl   = (float*)w;  w += sizeof(float) * (size_t)N_NODES * H;
  float* xr   = (float*)w;  w += sizeof(float) * (size_t)N_NODES * H;
  float* gate = (float*)w;  w += sizeof(float) * N_NODES;
  int* cnt    = (int*)w;    w += sizeof(int) * N_NODES;       // also fill positions
  int* rowp   = (int*)w;    w += sizeof(int) * (N_NODES + 1);
  int* col    = (int*)w;    w += sizeof(int) * EE;
  int* partial= (int*)w;    w += sizeof(int) * N_NODES;
  int* bsums  = (int*)w;    w += sizeof(int) * 256;
  int* gstart = (int*)w;    w += sizeof(int) * NGRAPH;
  int* gend   = (int*)w;    w += sizeof(int) * NGRAPH;
  float* pooled = (float*)w; w += sizeof(float) * NGRAPH * H;
  float* z      = (float*)w; w += sizeof(float) * NGRAPH * H;
  float* r1     = (float*)w; w += sizeof(float) * NGRAPH * 128;
  (void)ws_size; (void)n_in; (void)in_sizes; (void)out_size;

  const int* src = eidx;
  const int* dst = eidx + N_EDGES;
  int nblkN = (N_NODES + 255) / 256;
  int nblkE = (N_EDGES + 255) / 256;

  // CSR build (by dst, self-loops included)
  init_counts_kernel<<<nblkN, 256, 0, stream>>>(cnt);
  count_edges_kernel<<<nblkE, 256, 0, stream>>>(dst, cnt);
  scan_blocks_kernel<<<nblkN, 256, 0, stream>>>(cnt, partial, bsums, N_NODES);
  scan_sums_kernel<<<1, 256, 0, stream>>>(bsums, nblkN);
  scan_write_kernel<<<nblkN, 256, 0, stream>>>(partial, bsums, rowp, N_NODES);
  fill_self_kernel<<<nblkN, 256, 0, stream>>>(rowp, col, cnt);
  fill_edges_kernel<<<nblkE, 256, 0, stream>>>(src, dst, cnt, col);

  // input projection
  dim3 gproj(H / BN, (N_NODES + BM - 1) / BM);
  gemm_bias_kernel<<<gproj, 256, 0, stream>>>(x_in, W_in, b_in, x, N_NODES, IN_DIM, H, 0);

  dim3 glayer(H / BN, (N_NODES + BM - 1) / BM);
  int nblkV = N_NODES / 4;  // 12500, exact
  for (int l = 0; l < LAYERS; l++) {
    gemm_bias_kernel<<<glayer, 256, 0, stream>>>(x, Wl + (size_t)l * H * H, bl + l * H, xl, N_NODES, H, H, 0);
    gemm_bias_kernel<<<glayer, 256, 0, stream>>>(x, Wr + (size_t)l * H * H, br + l * H, xr, N_NODES, H, H, 0);
    layer_fused_kernel<<<nblkV, 256, 0, stream>>>(xl, xr, x, rowp, col,
        att + l * H, bias_c + l * H, ln_g + l * H, ln_b + l * H);
  }

  // gate MLP
  gemm_bias_kernel<<<glayer, 256, 0, stream>>>(x, Wg1, bg1, xl, N_NODES, H, H, 1);
  rowdot_kernel<<<nblkV, 256, 0, stream>>>(xl, Wg2, bg2, gate);

  // per-graph softmax pooling (batch is sorted)
  ginit_kernel<<<1, 64, 0, stream>>>(gstart, gend);
  gbounds_kernel<<<nblkN, 256, 0, stream>>>(batch, gstart, gend);
  pool_kernel<<<NGRAPH, 256, 0, stream>>>(gate, x, gstart, gend, pooled);

  // heads
  small_gemm_kernel<<<NGRAPH, 256, 0, stream>>>(pooled, Ws, bs, z, H, H, 1);
  small_gemm_kernel<<<NGRAPH, 256, 0, stream>>>(z, Wc, bc, out, H, NB, 0);
  small_gemm_kernel<<<NGRAPH, 256, 0, stream>>>(z, Wr1, br1, r1, H, 128, 1);
  residual_kernel<<<1, 64, 0, stream>>>(r1, Wr2, br2, out + (size_t)NGRAPH * NB);
}

// Round 2
// 916.223 us; speedup vs baseline: 1.9532x; 1.9532x over previous
//
#include <hip/hip_runtime.h>
#include <math.h>

#define N_NODES 50000
#define N_EDGES 300000
#define IN_DIM 64
#define H 256
#define LAYERS 4
#define NB 181
#define NGRAPH 64
#define EE (N_EDGES + N_NODES)
#define NEG_SLOPE 0.2f
#define LN_EPS 1e-5f

typedef unsigned short u16;
typedef __attribute__((ext_vector_type(8))) short short8;
typedef __attribute__((ext_vector_type(4))) float floatx4;

__device__ __forceinline__ u16 f2b(float f) {
  unsigned int u = __builtin_bit_cast(unsigned int, f);
  unsigned int r = (u + 0x7FFFu + ((u >> 16) & 1u)) >> 16;
  return (u16)r;
}

__device__ __forceinline__ float wave_reduce_sum(float v) {
  #pragma unroll
  for (int off = 32; off > 0; off >>= 1) v += __shfl_xor(v, off, 64);
  return v;
}

// ---------------- cast fp32 -> bf16 (vectorized, n must be /4) ----------------
__global__ void cast_bf16_kernel(const float* __restrict__ in, u16* __restrict__ out, int n4) {
  int i = blockIdx.x * 256 + threadIdx.x;
  if (i < n4) {
    float4 f = ((const float4*)in)[i];
    ushort4 o;
    o.x = f2b(f.x); o.y = f2b(f.y); o.z = f2b(f.z); o.w = f2b(f.w);
    ((ushort4*)out)[i] = o;
  }
}

// ---------------- CSR build ----------------
__global__ void init_counts_kernel(int* __restrict__ cnt) {
  int i = blockIdx.x * 256 + threadIdx.x;
  if (i < N_NODES) cnt[i] = 1;  // self loop
}

__global__ void count_edges_kernel(const int* __restrict__ dst, int* __restrict__ cnt) {
  int e = blockIdx.x * 256 + threadIdx.x;
  if (e < N_EDGES) atomicAdd(&cnt[dst[e]], 1);
}

__global__ void scan_blocks_kernel(const int* __restrict__ cnt, int* __restrict__ partial,
                                   int* __restrict__ bsums, int n) {
  __shared__ int buf[256];
  int tid = threadIdx.x;
  int i = blockIdx.x * 256 + tid;
  buf[tid] = (i < n) ? cnt[i] : 0;
  __syncthreads();
  #pragma unroll
  for (int off = 1; off < 256; off <<= 1) {
    int t = (tid >= off) ? buf[tid - off] : 0;
    __syncthreads();
    buf[tid] += t;
    __syncthreads();
  }
  if (i < n) partial[i] = buf[tid];
  if (tid == 255) bsums[blockIdx.x] = buf[255];
}

__global__ void scan_sums_kernel(int* __restrict__ bsums, int nblk) {
  __shared__ int buf[256];
  int tid = threadIdx.x;
  buf[tid] = (tid < nblk) ? bsums[tid] : 0;
  __syncthreads();
  #pragma unroll
  for (int off = 1; off < 256; off <<= 1) {
    int t = (tid >= off) ? buf[tid - off] : 0;
    __syncthreads();
    buf[tid] += t;
    __syncthreads();
  }
  if (tid < nblk) bsums[tid] = buf[tid];  // inclusive
}

__global__ void scan_write_kernel(const int* __restrict__ partial, const int* __restrict__ bsums,
                                  int* __restrict__ rowp, int n) {
  int i = blockIdx.x * 256 + threadIdx.x;
  if (i < n) {
    int b = blockIdx.x;
    int off = (b > 0) ? bsums[b - 1] : 0;
    rowp[i + 1] = partial[i] + off;
    if (i == 0) rowp[0] = 0;
  }
}

__global__ void fill_self_kernel(const int* __restrict__ rowp, int* __restrict__ col,
                                 int* __restrict__ fillpos) {
  int i = blockIdx.x * 256 + threadIdx.x;
  if (i < N_NODES) {
    int p = rowp[i];
    col[p] = i;
    fillpos[i] = p + 1;
  }
}

__global__ void fill_edges_kernel(const int* __restrict__ src, const int* __restrict__ dst,
                                  int* __restrict__ fillpos, int* __restrict__ col) {
  int e = blockIdx.x * 256 + threadIdx.x;
  if (e < N_EDGES) {
    int d = dst[e];
    int p = atomicAdd(&fillpos[d], 1);
    col[p] = src[e];
  }
}

// ---------------- MFMA GEMM: C[M,256] = A[M,K](bf16) @ W[256,K](bf16)^T + bias ----------------
// 128x128 block tile, TK=64, 4 waves in 2x2, each wave 64x64 (4x4 of 16x16x32 MFMA).
#define GTM 128
#define GTN 128
#define GTK 64
#define LDB 72  // LDS row stride in ushorts (144 B; /16 = 9, odd -> uniform b128 banks)

__global__ __launch_bounds__(256) void gemm_mfma_kernel(
    const u16* __restrict__ A, const u16* __restrict__ W,
    const float* __restrict__ bias, float* __restrict__ C,
    u16* __restrict__ Cbf, int M, int K, int relu)
{
  __shared__ u16 As[GTM * LDB];
  __shared__ u16 Bs[GTN * LDB];
  int tid = threadIdx.x;
  int lane = tid & 63;
  int wave = tid >> 6;
  int wm = (wave >> 1) * 64;
  int wn = (wave & 1) * 64;
  int bm = blockIdx.y * GTM;
  int bn = blockIdx.x * GTN;
  int lr = tid >> 3;          // 0..31
  int lc = (tid & 7) * 8;     // 0..56

  floatx4 zero4 = {0.f, 0.f, 0.f, 0.f};
  floatx4 acc[4][4];
  #pragma unroll
  for (int i = 0; i < 4; i++)
    #pragma unroll
    for (int j = 0; j < 4; j++) acc[i][j] = zero4;

  int q8 = (lane >> 4) * 8;
  int mrow = lane & 15;

  for (int k0 = 0; k0 < K; k0 += GTK) {
    __syncthreads();
    #pragma unroll
    for (int p = 0; p < 4; p++) {
      int row = lr + p * 32;
      int gr = bm + row;
      short8 av;
      if (gr < M) {
        av = *(const short8*)&A[(size_t)gr * K + k0 + lc];
      } else {
        #pragma unroll
        for (int z = 0; z < 8; z++) av[z] = 0;
      }
      *(short8*)&As[row * LDB + lc] = av;
      short8 bv = *(const short8*)&W[(size_t)(bn + row) * K + k0 + lc];
      *(short8*)&Bs[row * LDB + lc] = bv;
    }
    __syncthreads();
    #pragma unroll
    for (int h = 0; h < 2; h++) {
      short8 af[4], bf[4];
      #pragma unroll
      for (int i = 0; i < 4; i++)
        af[i] = *(const short8*)&As[(wm + i * 16 + mrow) * LDB + h * 32 + q8];
      #pragma unroll
      for (int j = 0; j < 4; j++)
        bf[j] = *(const short8*)&Bs[(wn + j * 16 + mrow) * LDB + h * 32 + q8];
      #pragma unroll
      for (int i = 0; i < 4; i++)
        #pragma unroll
        for (int j = 0; j < 4; j++)
          acc[i][j] = __builtin_amdgcn_mfma_f32_16x16x32_bf16(af[i], bf[j], acc[i][j], 0, 0, 0);
    }
  }

  // epilogue: D[row = quad*4 + r][col = lane&15]
  int ccol = lane & 15;
  int crow4 = (lane >> 4) * 4;
  #pragma unroll
  for (int j = 0; j < 4; j++) {
    int col = bn + wn + j * 16 + ccol;
    float bv = bias[col];
    #pragma unroll
    for (int i = 0; i < 4; i++) {
      #pragma unroll
      for (int r = 0; r < 4; r++) {
        int row = bm + wm + i * 16 + crow4 + r;
        if (row < M) {
          float v = acc[i][j][r] + bv;
          if (relu) v = fmaxf(v, 0.f);
          C[(size_t)row * H + col] = v;
          if (Cbf) Cbf[(size_t)row * H + col] = f2b(v);
        }
      }
    }
  }
}

// ---------------- fused edge softmax + aggregate + LN + residual ----------------
__global__ __launch_bounds__(256) void layer_fused_kernel(
    const float* __restrict__ xl, const float* __restrict__ xr,
    float* __restrict__ x, u16* __restrict__ xbf,
    const int* __restrict__ rowp, const int* __restrict__ col,
    const float* __restrict__ att, const float* __restrict__ bias_c,
    const float* __restrict__ ln_g, const float* __restrict__ ln_b)
{
  int lane = threadIdx.x & 63;
  int v = blockIdx.x * 4 + (threadIdx.x >> 6);
  if (v >= N_NODES) return;
  int f4 = lane << 2;
  size_t rowbase = (size_t)v * H;
  float4 xrv  = *(const float4*)&xr[rowbase + f4];
  float4 attv = *(const float4*)&att[f4];
  int beg = rowp[v], end = rowp[v + 1];
  float m = -INFINITY, d = 0.0f;
  float4 o = make_float4(0.f, 0.f, 0.f, 0.f);
  for (int p = beg; p < end; p++) {
    int u = col[p];
    float4 a = *(const float4*)&xl[(size_t)u * H + f4];
    float tx = a.x + xrv.x, ty = a.y + xrv.y, tz = a.z + xrv.z, tw = a.w + xrv.w;
    tx = tx > 0.f ? tx : NEG_SLOPE * tx;
    ty = ty > 0.f ? ty : NEG_SLOPE * ty;
    tz = tz > 0.f ? tz : NEG_SLOPE * tz;
    tw = tw > 0.f ? tw : NEG_SLOPE * tw;
    float pe = tx * attv.x + ty * attv.y + tz * attv.z + tw * attv.w;
    pe = wave_reduce_sum(pe);
    float mn  = fmaxf(m, pe);
    float sc  = __expf(m - mn);
    float wgt = __expf(pe - mn);
    d = d * sc + wgt;
    o.x = o.x * sc + wgt * a.x;
    o.y = o.y * sc + wgt * a.y;
    o.z = o.z * sc + wgt * a.z;
    o.w = o.w * sc + wgt * a.w;
    m = mn;
  }
  float invd = 1.0f / d;
  float4 bc4 = *(const float4*)&bias_c[f4];
  float ox = o.x * invd + bc4.x;
  float oy = o.y * invd + bc4.y;
  float oz = o.z * invd + bc4.z;
  float ow = o.w * invd + bc4.w;
  float s = wave_reduce_sum(ox + oy + oz + ow);
  float mean = s * (1.0f / H);
  float cx = ox - mean, cy = oy - mean, cz = oz - mean, cw = ow - mean;
  float sq = wave_reduce_sum(cx * cx + cy * cy + cz * cz + cw * cw);
  float rstd = rsqrtf(sq * (1.0f / H) + LN_EPS);
  float4 g4 = *(const float4*)&ln_g[f4];
  float4 b4 = *(const float4*)&ln_b[f4];
  float4 xres = *(const float4*)&x[rowbase + f4];
  float4 y;
  y.x = fmaxf(cx * rstd * g4.x + b4.x, 0.f) + xres.x;
  y.y = fmaxf(cy * rstd * g4.y + b4.y, 0.f) + xres.y;
  y.z = fmaxf(cz * rstd * g4.z + b4.z, 0.f) + xres.z;
  y.w = fmaxf(cw * rstd * g4.w + b4.w, 0.f) + xres.w;
  *(float4*)&x[rowbase + f4] = y;
  ushort4 yb;
  yb.x = f2b(y.x); yb.y = f2b(y.y); yb.z = f2b(y.z); yb.w = f2b(y.w);
  *(ushort4*)&xbf[rowbase + f4] = yb;
}

// ---------------- gate scalar ----------------
__global__ __launch_bounds__(256) void rowdot_kernel(
    const float* __restrict__ hidden, const float* __restrict__ Wg2,
    const float* __restrict__ bg2, float* __restrict__ gate)
{
  int lane = threadIdx.x & 63;
  int v = blockIdx.x * 4 + (threadIdx.x >> 6);
  if (v >= N_NODES) return;
  int f4 = lane << 2;
  float4 hv = *(const float4*)&hidden[(size_t)v * H + f4];
  float4 wv = *(const float4*)&Wg2[f4];
  float p = hv.x * wv.x + hv.y * wv.y + hv.z * wv.z + hv.w * wv.w;
  p = wave_reduce_sum(p);
  if (lane == 0) gate[v] = p + bg2[0];
}

// ---------------- graph bounds (batch is sorted -> neighbor compare, no atomics) ----------------
__global__ void ginit_kernel(int* __restrict__ gstart, int* __restrict__ gend) {
  int t = threadIdx.x;
  if (t < NGRAPH) { gstart[t] = N_NODES; gend[t] = 0; }
}

__global__ void gbounds_kernel(const int* __restrict__ batch, int* __restrict__ gstart,
                               int* __restrict__ gend) {
  int i = blockIdx.x * 256 + threadIdx.x;
  if (i < N_NODES) {
    int b = batch[i];
    if (i == 0 || batch[i - 1] != b) gstart[b] = i;
    if (i == N_NODES - 1 || batch[i + 1] != b) gend[b] = i + 1;
  }
}

// ---------------- pooling ----------------
__global__ __launch_bounds__(256) void pool_kernel(
    const float* __restrict__ gate, const float* __restrict__ x,
    const int* __restrict__ gstart, const int* __restrict__ gend,
    float* __restrict__ pooled)
{
  __shared__ float red[256];
  __shared__ float wl[256];
  int g = blockIdx.x, tid = threadIdx.x;
  int s = gstart[g], e = gend[g];
  float acc = 0.0f;
  if (s < e) {
    float lm = -INFINITY;
    for (int i = s + tid; i < e; i += 256) lm = fmaxf(lm, gate[i]);
    red[tid] = lm;
    __syncthreads();
    for (int off = 128; off; off >>= 1) {
      if (tid < off) red[tid] = fmaxf(red[tid], red[tid + off]);
      __syncthreads();
    }
    float m = red[0];
    __syncthreads();
    float lsum = 0.0f;
    for (int i = s + tid; i < e; i += 256) lsum += __expf(gate[i] - m);
    red[tid] = lsum;
    __syncthreads();
    for (int off = 128; off; off >>= 1) {
      if (tid < off) red[tid] += red[tid + off];
      __syncthreads();
    }
    float invd = 1.0f / red[0];
    __syncthreads();
    for (int s0 = s; s0 < e; s0 += 256) {
      int c = min(256, e - s0);
      wl[tid] = (tid < c) ? __expf(gate[s0 + tid] - m) * invd : 0.0f;
      __syncthreads();
      for (int j = 0; j < c; j++) acc += wl[j] * x[(size_t)(s0 + j) * H + tid];
      __syncthreads();
    }
  }
  pooled[(size_t)g * H + tid] = acc;
}

// ---------------- small GEMM (G rows) ----------------
__global__ __launch_bounds__(256) void small_gemm_kernel(
    const float* __restrict__ A, const float* __restrict__ W,
    const float* __restrict__ bias, float* __restrict__ C,
    int K, int Nc, int relu)
{
  __shared__ float arow[256];
  int g = blockIdx.x, j = threadIdx.x;
  if (j < K) arow[j] = A[(size_t)g * K + j];
  __syncthreads();
  if (j >= Nc) return;
  float acc = bias[j];
  const float4* wr = (const float4*)&W[(size_t)j * K];
  for (int k4 = 0; k4 < K / 4; k4++) {
    float4 wv = wr[k4];
    float4 av = *(const float4*)&arow[k4 * 4];
    acc += av.x * wv.x + av.y * wv.y + av.z * wv.z + av.w * wv.w;
  }
  if (relu) acc = fmaxf(acc, 0.f);
  C[(size_t)g * Nc + j] = acc;
}

__global__ void residual_kernel(const float* __restrict__ r1, const float* __restrict__ Wr2,
                                const float* __restrict__ br2, float* __restrict__ out) {
  int g = threadIdx.x;
  if (g < NGRAPH) {
    float acc = br2[0];
    for (int k = 0; k < 128; k++) acc += r1[(size_t)g * 128 + k] * Wr2[k];
    out[g] = tanhf(acc);
  }
}

// ---------------- launcher ----------------
extern "C" void kernel_launch(void* const* d_in, const int* in_sizes, int n_in,
                              void* d_out, int out_size, void* d_ws, size_t ws_size,
                              hipStream_t stream) {
  const float* x_in   = (const float*)d_in[0];
  const int*   eidx   = (const int*)d_in[1];
  const int*   batch  = (const int*)d_in[2];
  const float* W_in   = (const float*)d_in[3];
  const float* b_in   = (const float*)d_in[4];
  const float* Wl     = (const float*)d_in[5];
  const float* bl     = (const float*)d_in[6];
  const float* Wr     = (const float*)d_in[7];
  const float* br     = (const float*)d_in[8];
  const float* att    = (const float*)d_in[9];
  const float* bias_c = (const float*)d_in[10];
  const float* ln_g   = (const float*)d_in[11];
  const float* ln_b   = (const float*)d_in[12];
  const float* Wg1    = (const float*)d_in[13];
  const float* bg1    = (const float*)d_in[14];
  const float* Wg2    = (const float*)d_in[15];
  const float* bg2    = (const float*)d_in[16];
  const float* Ws     = (const float*)d_in[17];
  const float* bs     = (const float*)d_in[18];
  const float* Wc     = (const float*)d_in[19];
  const float* bc     = (const float*)d_in[20];
  const float* Wr1    = (const float*)d_in[21];
  const float* br1    = (const float*)d_in[22];
  const float* Wr2    = (const float*)d_in[23];
  const float* br2    = (const float*)d_in[24];
  float* out = (float*)d_out;

  char* w = (char*)d_ws;
  float* x    = (float*)w;  w += sizeof(float) * (size_t)N_NODES * H;
  float* xl   = (float*)w;  w += sizeof(float) * (size_t)N_NODES * H;
  float* xr   = (float*)w;  w += sizeof(float) * (size_t)N_NODES * H;
  u16* x_bf   = (u16*)w;    w += sizeof(u16) * (size_t)N_NODES * H;
  u16* xin_bf = (u16*)w;    w += sizeof(u16) * (size_t)N_NODES * IN_DIM;
  u16* win_bf = (u16*)w;    w += sizeof(u16) * (size_t)H * IN_DIM;
  u16* wl_bf  = (u16*)w;    w += sizeof(u16) * (size_t)LAYERS * H * H;
  u16* wr_bf  = (u16*)w;    w += sizeof(u16) * (size_t)LAYERS * H * H;
  u16* wg1_bf = (u16*)w;    w += sizeof(u16) * (size_t)H * H;
  float* pooled = (float*)w; w += sizeof(float) * NGRAPH * H;
  float* z      = (float*)w; w += sizeof(float) * NGRAPH * H;
  float* r1     = (float*)w; w += sizeof(float) * NGRAPH * 128;
  float* gate = (float*)w;  w += sizeof(float) * N_NODES;
  int* cnt    = (int*)w;    w += sizeof(int) * N_NODES;       // also fill positions
  int* rowp   = (int*)w;    w += sizeof(int) * (N_NODES + 1);
  int* col    = (int*)w;    w += sizeof(int) * EE;
  int* partial= (int*)w;    w += sizeof(int) * N_NODES;
  int* bsums  = (int*)w;    w += sizeof(int) * 256;
  int* gstart = (int*)w;    w += sizeof(int) * NGRAPH;
  int* gend   = (int*)w;    w += sizeof(int) * NGRAPH;
  (void)ws_size; (void)n_in; (void)in_sizes; (void)out_size;

  const int* src = eidx;
  const int* dst = eidx + N_EDGES;
  int nblkN = (N_NODES + 255) / 256;
  int nblkE = (N_EDGES + 255) / 256;

  // CSR build (by dst, self-loops included)
  init_counts_kernel<<<nblkN, 256, 0, stream>>>(cnt);
  count_edges_kernel<<<nblkE, 256, 0, stream>>>(dst, cnt);
  scan_blocks_kernel<<<nblkN, 256, 0, stream>>>(cnt, partial, bsums, N_NODES);
  scan_sums_kernel<<<1, 256, 0, stream>>>(bsums, nblkN);
  scan_write_kernel<<<nblkN, 256, 0, stream>>>(partial, bsums, rowp, N_NODES);
  fill_self_kernel<<<nblkN, 256, 0, stream>>>(rowp, col, cnt);
  fill_edges_kernel<<<nblkE, 256, 0, stream>>>(src, dst, cnt, col);

  // weight + input casts to bf16
  auto cast = [&](const float* src_f, u16* dst_b, int n) {
    int n4 = n / 4;
    cast_bf16_kernel<<<(n4 + 255) / 256, 256, 0, stream>>>(src_f, dst_b, n4);
  };
  cast(W_in, win_bf, H * IN_DIM);
  cast(Wl, wl_bf, LAYERS * H * H);
  cast(Wr, wr_bf, LAYERS * H * H);
  cast(Wg1, wg1_bf, H * H);
  cast(x_in, xin_bf, N_NODES * IN_DIM);

  // input projection (writes fp32 x + bf16 x_bf)
  dim3 ggrid(H / GTN, (N_NODES + GTM - 1) / GTM);
  gemm_mfma_kernel<<<ggrid, 256, 0, stream>>>(xin_bf, win_bf, b_in, x, x_bf, N_NODES, IN_DIM, 0);

  int nblkV = N_NODES / 4;  // 12500, exact
  for (int l = 0; l < LAYERS; l++) {
    gemm_mfma_kernel<<<ggrid, 256, 0, stream>>>(x_bf, wl_bf + (size_t)l * H * H, bl + l * H, xl, nullptr, N_NODES, H, 0);
    gemm_mfma_kernel<<<ggrid, 256, 0, stream>>>(x_bf, wr_bf + (size_t)l * H * H, br + l * H, xr, nullptr, N_NODES, H, 0);
    layer_fused_kernel<<<nblkV, 256, 0, stream>>>(xl, xr, x, x_bf, rowp, col,
        att + l * H, bias_c + l * H, ln_g + l * H, ln_b + l * H);
  }

  // gate MLP
  gemm_mfma_kernel<<<ggrid, 256, 0, stream>>>(x_bf, wg1_bf, bg1, xl, nullptr, N_NODES, H, 1);
  rowdot_kernel<<<nblkV, 256, 0, stream>>>(xl, Wg2, bg2, gate);

  // per-graph softmax pooling (batch is sorted)
  ginit_kernel<<<1, 64, 0, stream>>>(gstart, gend);
  gbounds_kernel<<<nblkN, 256, 0, stream>>>(batch, gstart, gend);
  pool_kernel<<<NGRAPH, 256, 0, stream>>>(gate, x, gstart, gend, pooled);

  // heads (fp32, tiny)
  small_gemm_kernel<<<NGRAPH, 256, 0, stream>>>(pooled, Ws, bs, z, H, H, 1);
  small_gemm_kernel<<<NGRAPH, 256, 0, stream>>>(z, Wc, bc, out, H, NB, 0);
  small_gemm_kernel<<<NGRAPH, 256, 0, stream>>>(z, Wr1, br1, r1, H, 128, 1);
  residual_kernel<<<1, 64, 0, stream>>>(r1, Wr2, br2, out + (size_t)NGRAPH * NB);
}

// Round 4
// 780.439 us; speedup vs baseline: 2.2930x; 1.1740x over previous
//
#include <hip/hip_runtime.h>
#include <math.h>

#define N_NODES 50000
#define N_EDGES 300000
#define IN_DIM 64
#define H 256
#define LAYERS 4
#define NB 181
#define NGRAPH 64
#define EE (N_EDGES + N_NODES)
#define NEG_SLOPE 0.2f
#define LN_EPS 1e-5f

typedef unsigned short u16;
typedef __attribute__((ext_vector_type(8))) short short8;
typedef __attribute__((ext_vector_type(4))) float floatx4;

__device__ __forceinline__ u16 f2b(float f) {
  unsigned int u = __builtin_bit_cast(unsigned int, f);
  unsigned int r = (u + 0x7FFFu + ((u >> 16) & 1u)) >> 16;
  return (u16)r;
}
__device__ __forceinline__ float b2f(u16 b) {
  return __builtin_bit_cast(float, ((unsigned int)b) << 16);
}

__device__ __forceinline__ float wave_reduce_sum(float v) {
  #pragma unroll
  for (int off = 32; off > 0; off >>= 1) v += __shfl_xor(v, off, 64);
  return v;
}

// ---------------- cast fp32 -> bf16 ----------------
__global__ void cast_bf16_kernel(const float* __restrict__ in, u16* __restrict__ out, int n4) {
  int i = blockIdx.x * 256 + threadIdx.x;
  if (i < n4) {
    float4 f = ((const float4*)in)[i];
    ushort4 o;
    o.x = f2b(f.x); o.y = f2b(f.y); o.z = f2b(f.z); o.w = f2b(f.w);
    ((ushort4*)out)[i] = o;
  }
}

// ---------------- CSR build ----------------
__global__ void init_counts_kernel(int* __restrict__ cnt) {
  int i = blockIdx.x * 256 + threadIdx.x;
  if (i < N_NODES) cnt[i] = 1;  // self loop
}

__global__ void count_edges_kernel(const int* __restrict__ dst, int* __restrict__ cnt) {
  int e = blockIdx.x * 256 + threadIdx.x;
  if (e < N_EDGES) atomicAdd(&cnt[dst[e]], 1);
}

__global__ void scan_blocks_kernel(const int* __restrict__ cnt, int* __restrict__ partial,
                                   int* __restrict__ bsums, int n) {
  __shared__ int buf[256];
  int tid = threadIdx.x;
  int i = blockIdx.x * 256 + tid;
  buf[tid] = (i < n) ? cnt[i] : 0;
  __syncthreads();
  #pragma unroll
  for (int off = 1; off < 256; off <<= 1) {
    int t = (tid >= off) ? buf[tid - off] : 0;
    __syncthreads();
    buf[tid] += t;
    __syncthreads();
  }
  if (i < n) partial[i] = buf[tid];
  if (tid == 255) bsums[blockIdx.x] = buf[255];
}

__global__ void scan_sums_kernel(int* __restrict__ bsums, int nblk) {
  __shared__ int buf[256];
  int tid = threadIdx.x;
  buf[tid] = (tid < nblk) ? bsums[tid] : 0;
  __syncthreads();
  #pragma unroll
  for (int off = 1; off < 256; off <<= 1) {
    int t = (tid >= off) ? buf[tid - off] : 0;
    __syncthreads();
    buf[tid] += t;
    __syncthreads();
  }
  if (tid < nblk) bsums[tid] = buf[tid];
}

__global__ void scan_write_kernel(const int* __restrict__ partial, const int* __restrict__ bsums,
                                  int* __restrict__ rowp, int n) {
  int i = blockIdx.x * 256 + threadIdx.x;
  if (i < n) {
    int b = blockIdx.x;
    int off = (b > 0) ? bsums[b - 1] : 0;
    rowp[i + 1] = partial[i] + off;
    if (i == 0) rowp[0] = 0;
  }
}

__global__ void fill_self_kernel(const int* __restrict__ rowp, int* __restrict__ col,
                                 int* __restrict__ fillpos) {
  int i = blockIdx.x * 256 + threadIdx.x;
  if (i < N_NODES) {
    int p = rowp[i];
    col[p] = i;
    fillpos[i] = p + 1;
  }
}

__global__ void fill_edges_kernel(const int* __restrict__ src, const int* __restrict__ dst,
                                  int* __restrict__ fillpos, int* __restrict__ col) {
  int e = blockIdx.x * 256 + threadIdx.x;
  if (e < N_EDGES) {
    int d = dst[e];
    int p = atomicAdd(&fillpos[d], 1);
    col[p] = src[e];
  }
}

// ---------------- MFMA GEMM tiles ----------------
#define GTM 128
#define GTN 128
#define GTK 64
#define LDB 72

// input projection: C[M,256] = A[M,K]@W^T + bias; writes fp32 C and bf16 Cbf
__global__ __launch_bounds__(256) void gemm_mfma_kernel(
    const u16* __restrict__ A, const u16* __restrict__ W,
    const float* __restrict__ bias, float* __restrict__ C,
    u16* __restrict__ Cbf, int M, int K)
{
  __shared__ u16 As[GTM * LDB];
  __shared__ u16 Bs[GTN * LDB];
  int tid = threadIdx.x;
  int lane = tid & 63;
  int wave = tid >> 6;
  int wm = (wave >> 1) * 64;
  int wn = (wave & 1) * 64;
  int bm = blockIdx.y * GTM;
  int bn = blockIdx.x * GTN;
  int lr = tid >> 3;
  int lc = (tid & 7) * 8;

  floatx4 zero4 = {0.f, 0.f, 0.f, 0.f};
  floatx4 acc[4][4];
  #pragma unroll
  for (int i = 0; i < 4; i++)
    #pragma unroll
    for (int j = 0; j < 4; j++) acc[i][j] = zero4;

  int q8 = (lane >> 4) * 8;
  int mrow = lane & 15;

  for (int k0 = 0; k0 < K; k0 += GTK) {
    __syncthreads();
    #pragma unroll
    for (int p = 0; p < 4; p++) {
      int row = lr + p * 32;
      int gr = bm + row;
      short8 av = {0, 0, 0, 0, 0, 0, 0, 0};
      if (gr < M) av = *(const short8*)&A[(size_t)gr * K + k0 + lc];
      *(short8*)&As[row * LDB + lc] = av;
      short8 bv = *(const short8*)&W[(size_t)(bn + row) * K + k0 + lc];
      *(short8*)&Bs[row * LDB + lc] = bv;
    }
    __syncthreads();
    #pragma unroll
    for (int h = 0; h < 2; h++) {
      short8 af[4], bf[4];
      #pragma unroll
      for (int i = 0; i < 4; i++)
        af[i] = *(const short8*)&As[(wm + i * 16 + mrow) * LDB + h * 32 + q8];
      #pragma unroll
      for (int j = 0; j < 4; j++)
        bf[j] = *(const short8*)&Bs[(wn + j * 16 + mrow) * LDB + h * 32 + q8];
      #pragma unroll
      for (int i = 0; i < 4; i++)
        #pragma unroll
        for (int j = 0; j < 4; j++)
          acc[i][j] = __builtin_amdgcn_mfma_f32_16x16x32_bf16(af[i], bf[j], acc[i][j], 0, 0, 0);
    }
  }

  int ccol = lane & 15;
  int crow4 = (lane >> 4) * 4;
  #pragma unroll
  for (int j = 0; j < 4; j++) {
    int col = bn + wn + j * 16 + ccol;
    float bv = bias[col];
    #pragma unroll
    for (int i = 0; i < 4; i++) {
      #pragma unroll
      for (int r = 0; r < 4; r++) {
        int row = bm + wm + i * 16 + crow4 + r;
        if (row < M) {
          float v = acc[i][j][r] + bv;
          C[(size_t)row * H + col] = v;
          Cbf[(size_t)row * H + col] = f2b(v);
        }
      }
    }
  }
}

// dual GEMM: cols 0..255 -> Wl -> outL; cols 256..511 -> Wr -> outR (bf16 out only)
__global__ __launch_bounds__(256) void gemm_mfma_dual_kernel(
    const u16* __restrict__ A, const u16* __restrict__ Wlb, const u16* __restrict__ Wrb,
    const float* __restrict__ biasL, const float* __restrict__ biasR,
    u16* __restrict__ outL, u16* __restrict__ outR, int M)
{
  __shared__ u16 As[GTM * LDB];
  __shared__ u16 Bs[GTN * LDB];
  int tid = threadIdx.x;
  int lane = tid & 63;
  int wave = tid >> 6;
  int wm = (wave >> 1) * 64;
  int wn = (wave & 1) * 64;
  int bm = blockIdx.y * GTM;
  int bnAll = blockIdx.x * GTN;
  const u16* W = (bnAll < H) ? Wlb : Wrb;
  const float* bias = (bnAll < H) ? biasL : biasR;
  u16* outp = (bnAll < H) ? outL : outR;
  int n0 = bnAll & (H - 1);
  int lr = tid >> 3;
  int lc = (tid & 7) * 8;

  floatx4 zero4 = {0.f, 0.f, 0.f, 0.f};
  floatx4 acc[4][4];
  #pragma unroll
  for (int i = 0; i < 4; i++)
    #pragma unroll
    for (int j = 0; j < 4; j++) acc[i][j] = zero4;

  int q8 = (lane >> 4) * 8;
  int mrow = lane & 15;

  for (int k0 = 0; k0 < H; k0 += GTK) {
    __syncthreads();
    #pragma unroll
    for (int p = 0; p < 4; p++) {
      int row = lr + p * 32;
      int gr = bm + row;
      short8 av = {0, 0, 0, 0, 0, 0, 0, 0};
      if (gr < M) av = *(const short8*)&A[(size_t)gr * H + k0 + lc];
      *(short8*)&As[row * LDB + lc] = av;
      short8 bv = *(const short8*)&W[(size_t)(n0 + row) * H + k0 + lc];
      *(short8*)&Bs[row * LDB + lc] = bv;
    }
    __syncthreads();
    #pragma unroll
    for (int h = 0; h < 2; h++) {
      short8 af[4], bf[4];
      #pragma unroll
      for (int i = 0; i < 4; i++)
        af[i] = *(const short8*)&As[(wm + i * 16 + mrow) * LDB + h * 32 + q8];
      #pragma unroll
      for (int j = 0; j < 4; j++)
        bf[j] = *(const short8*)&Bs[(wn + j * 16 + mrow) * LDB + h * 32 + q8];
      #pragma unroll
      for (int i = 0; i < 4; i++)
        #pragma unroll
        for (int j = 0; j < 4; j++)
          acc[i][j] = __builtin_amdgcn_mfma_f32_16x16x32_bf16(af[i], bf[j], acc[i][j], 0, 0, 0);
    }
  }

  int ccol = lane & 15;
  int crow4 = (lane >> 4) * 4;
  #pragma unroll
  for (int j = 0; j < 4; j++) {
    int col = n0 + wn + j * 16 + ccol;
    float bv = bias[col];
    #pragma unroll
    for (int i = 0; i < 4; i++) {
      #pragma unroll
      for (int r = 0; r < 4; r++) {
        int row = bm + wm + i * 16 + crow4 + r;
        if (row < M) {
          outp[(size_t)row * H + col] = f2b(acc[i][j][r] + bv);
        }
      }
    }
  }
}

// gate GEMM: gate[row] += sum_col relu(x@Wg1 + bg1)[col] * Wg2[col]; gate pre-init to bg2
__global__ __launch_bounds__(256) void gemm_gate_kernel(
    const u16* __restrict__ A, const u16* __restrict__ W,
    const float* __restrict__ bias, const float* __restrict__ Wg2,
    float* __restrict__ gate, int M)
{
  __shared__ u16 As[GTM * LDB];
  __shared__ u16 Bs[GTN * LDB];
  int tid = threadIdx.x;
  int lane = tid & 63;
  int wave = tid >> 6;
  int wm = (wave >> 1) * 64;
  int wn = (wave & 1) * 64;
  int bm = blockIdx.y * GTM;
  int bn = blockIdx.x * GTN;
  int lr = tid >> 3;
  int lc = (tid & 7) * 8;

  floatx4 zero4 = {0.f, 0.f, 0.f, 0.f};
  floatx4 acc[4][4];
  #pragma unroll
  for (int i = 0; i < 4; i++)
    #pragma unroll
    for (int j = 0; j < 4; j++) acc[i][j] = zero4;

  int q8 = (lane >> 4) * 8;
  int mrow = lane & 15;

  for (int k0 = 0; k0 < H; k0 += GTK) {
    __syncthreads();
    #pragma unroll
    for (int p = 0; p < 4; p++) {
      int row = lr + p * 32;
      int gr = bm + row;
      short8 av = {0, 0, 0, 0, 0, 0, 0, 0};
      if (gr < M) av = *(const short8*)&A[(size_t)gr * H + k0 + lc];
      *(short8*)&As[row * LDB + lc] = av;
      short8 bv = *(const short8*)&W[(size_t)(bn + row) * H + k0 + lc];
      *(short8*)&Bs[row * LDB + lc] = bv;
    }
    __syncthreads();
    #pragma unroll
    for (int h = 0; h < 2; h++) {
      short8 af[4], bf[4];
      #pragma unroll
      for (int i = 0; i < 4; i++)
        af[i] = *(const short8*)&As[(wm + i * 16 + mrow) * LDB + h * 32 + q8];
      #pragma unroll
      for (int j = 0; j < 4; j++)
        bf[j] = *(const short8*)&Bs[(wn + j * 16 + mrow) * LDB + h * 32 + q8];
      #pragma unroll
      for (int i = 0; i < 4; i++)
        #pragma unroll
        for (int j = 0; j < 4; j++)
          acc[i][j] = __builtin_amdgcn_mfma_f32_16x16x32_bf16(af[i], bf[j], acc[i][j], 0, 0, 0);
    }
  }

  int ccol = lane & 15;
  float bv[4], wv[4];
  #pragma unroll
  for (int j = 0; j < 4; j++) {
    int col = bn + wn + j * 16 + ccol;
    bv[j] = bias[col];
    wv[j] = Wg2[col];
  }
  #pragma unroll
  for (int i = 0; i < 4; i++) {
    #pragma unroll
    for (int r = 0; r < 4; r++) {
      float p = 0.f;
      #pragma unroll
      for (int j = 0; j < 4; j++) {
        float hcol = fmaxf(acc[i][j][r] + bv[j], 0.f);
        p += hcol * wv[j];
      }
      p += __shfl_xor(p, 1, 64);
      p += __shfl_xor(p, 2, 64);
      p += __shfl_xor(p, 4, 64);
      p += __shfl_xor(p, 8, 64);
      int row = bm + wm + i * 16 + (lane >> 4) * 4 + r;
      if ((lane & 15) == 0 && row < M) atomicAdd(&gate[row], p);
    }
  }
}

// ---------------- fused edge softmax + aggregate + LN + residual (bf16 gathers) ----------------
__global__ __launch_bounds__(256) void layer_fused_kernel(
    const u16* __restrict__ xl, const u16* __restrict__ xr,
    float* __restrict__ x, u16* __restrict__ xbf,
    const int* __restrict__ rowp, const int* __restrict__ col,
    const float* __restrict__ att, const float* __restrict__ bias_c,
    const float* __restrict__ ln_g, const float* __restrict__ ln_b)
{
  int lane = threadIdx.x & 63;
  int v = blockIdx.x * 4 + (threadIdx.x >> 6);
  if (v >= N_NODES) return;
  int f4 = lane << 2;
  size_t rowbase = (size_t)v * H;
  ushort4 xr4 = *(const ushort4*)&xr[rowbase + f4];
  float4 xrv = make_float4(b2f(xr4.x), b2f(xr4.y), b2f(xr4.z), b2f(xr4.w));
  float4 attv = *(const float4*)&att[f4];
  int beg = rowp[v], end = rowp[v + 1];
  float m = -INFINITY, d = 0.0f;
  float4 o = make_float4(0.f, 0.f, 0.f, 0.f);
  for (int p = beg; p < end; p++) {
    int u = col[p];
    ushort4 a4 = *(const ushort4*)&xl[(size_t)u * H + f4];
    float ax = b2f(a4.x), ay = b2f(a4.y), az = b2f(a4.z), aw = b2f(a4.w);
    float tx = ax + xrv.x, ty = ay + xrv.y, tz = az + xrv.z, tw = aw + xrv.w;
    tx = tx > 0.f ? tx : NEG_SLOPE * tx;
    ty = ty > 0.f ? ty : NEG_SLOPE * ty;
    tz = tz > 0.f ? tz : NEG_SLOPE * tz;
    tw = tw > 0.f ? tw : NEG_SLOPE * tw;
    float pe = tx * attv.x + ty * attv.y + tz * attv.z + tw * attv.w;
    pe = wave_reduce_sum(pe);
    float mn  = fmaxf(m, pe);
    float sc  = __expf(m - mn);
    float wgt = __expf(pe - mn);
    d = d * sc + wgt;
    o.x = o.x * sc + wgt * ax;
    o.y = o.y * sc + wgt * ay;
    o.z = o.z * sc + wgt * az;
    o.w = o.w * sc + wgt * aw;
    m = mn;
  }
  float invd = 1.0f / d;
  float4 bc4 = *(const float4*)&bias_c[f4];
  float ox = o.x * invd + bc4.x;
  float oy = o.y * invd + bc4.y;
  float oz = o.z * invd + bc4.z;
  float ow = o.w * invd + bc4.w;
  float s = wave_reduce_sum(ox + oy + oz + ow);
  float mean = s * (1.0f / H);
  float cx = ox - mean, cy = oy - mean, cz = oz - mean, cw = ow - mean;
  float sq = wave_reduce_sum(cx * cx + cy * cy + cz * cz + cw * cw);
  float rstd = rsqrtf(sq * (1.0f / H) + LN_EPS);
  float4 g4 = *(const float4*)&ln_g[f4];
  float4 b4 = *(const float4*)&ln_b[f4];
  float4 xres = *(const float4*)&x[rowbase + f4];
  float4 y;
  y.x = fmaxf(cx * rstd * g4.x + b4.x, 0.f) + xres.x;
  y.y = fmaxf(cy * rstd * g4.y + b4.y, 0.f) + xres.y;
  y.z = fmaxf(cz * rstd * g4.z + b4.z, 0.f) + xres.z;
  y.w = fmaxf(cw * rstd * g4.w + b4.w, 0.f) + xres.w;
  *(float4*)&x[rowbase + f4] = y;
  ushort4 yb;
  yb.x = f2b(y.x); yb.y = f2b(y.y); yb.z = f2b(y.z); yb.w = f2b(y.w);
  *(ushort4*)&xbf[rowbase + f4] = yb;
}

// ---------------- gate init ----------------
__global__ void gate_init_kernel(float* __restrict__ gate, const float* __restrict__ bg2) {
  int i = blockIdx.x * 256 + threadIdx.x;
  if (i < N_NODES) gate[i] = bg2[0];
}

// ---------------- graph bounds (sorted batch) ----------------
__global__ void ginit_kernel(int* __restrict__ gstart, int* __restrict__ gend) {
  int t = threadIdx.x;
  if (t < NGRAPH) { gstart[t] = N_NODES; gend[t] = 0; }
}

__global__ void gbounds_kernel(const int* __restrict__ batch, int* __restrict__ gstart,
                               int* __restrict__ gend) {
  int i = blockIdx.x * 256 + threadIdx.x;
  if (i < N_NODES) {
    int b = batch[i];
    if (i == 0 || batch[i - 1] != b) gstart[b] = i;
    if (i == N_NODES - 1 || batch[i + 1] != b) gend[b] = i + 1;
  }
}

// ---------------- pooling: per-graph softmax stats ----------------
__global__ __launch_bounds__(256) void pool_prep_kernel(
    const float* __restrict__ gate, const int* __restrict__ gstart,
    const int* __restrict__ gend, float* __restrict__ gmax, float* __restrict__ gdinv)
{
  __shared__ float red[256];
  int g = blockIdx.x, tid = threadIdx.x;
  int s = gstart[g], e = gend[g];
  float lm = -INFINITY;
  for (int i = s + tid; i < e; i += 256) lm = fmaxf(lm, gate[i]);
  red[tid] = lm;
  __syncthreads();
  for (int off = 128; off; off >>= 1) {
    if (tid < off) red[tid] = fmaxf(red[tid], red[tid + off]);
    __syncthreads();
  }
  float m = red[0];
  __syncthreads();
  float lsum = 0.0f;
  for (int i = s + tid; i < e; i += 256) lsum += __expf(gate[i] - m);
  red[tid] = lsum;
  __syncthreads();
  for (int off = 128; off; off >>= 1) {
    if (tid < off) red[tid] += red[tid + off];
    __syncthreads();
  }
  if (tid == 0) {
    gmax[g] = m;
    gdinv[g] = (s < e) ? 1.0f / red[0] : 0.0f;
  }
}

// ---------------- pooled zero init ----------------
__global__ void pool_zero_kernel(float* __restrict__ pooled) {
  int i = blockIdx.x * 256 + threadIdx.x;
  if (i < NGRAPH * H) pooled[i] = 0.f;
}

// ---------------- pooling: weighted accumulate (128 nodes per block) ----------------
__global__ __launch_bounds__(256) void pool_accum_kernel(
    const float* __restrict__ gate, const float* __restrict__ x,
    const int* __restrict__ batch, const float* __restrict__ gmax,
    const float* __restrict__ gdinv, float* __restrict__ pooled)
{
  __shared__ float wl[128];
  __shared__ int gl[128];
  int b0 = blockIdx.x * 128;
  int tid = threadIdx.x;
  if (tid < 128) {
    int v = b0 + tid;
    if (v < N_NODES) {
      int g = batch[v];
      gl[tid] = g;
      wl[tid] = __expf(gate[v] - gmax[g]) * gdinv[g];
    } else {
      gl[tid] = -1;
      wl[tid] = 0.f;
    }
  }
  __syncthreads();
  int cnt = min(128, N_NODES - b0);
  float acc = 0.f;
  int cur = gl[0];
  for (int j = 0; j < cnt; j++) {
    int g = gl[j];
    if (g != cur) {
      atomicAdd(&pooled[(size_t)cur * H + tid], acc);
      acc = 0.f;
      cur = g;
    }
    acc += wl[j] * x[(size_t)(b0 + j) * H + tid];
  }
  if (cur >= 0) atomicAdd(&pooled[(size_t)cur * H + tid], acc);
}

// ---------------- small GEMM (G rows) ----------------
__global__ __launch_bounds__(256) void small_gemm_kernel(
    const float* __restrict__ A, const float* __restrict__ W,
    const float* __restrict__ bias, float* __restrict__ C,
    int K, int Nc, int relu)
{
  __shared__ float arow[256];
  int g = blockIdx.x, j = threadIdx.x;
  if (j < K) arow[j] = A[(size_t)g * K + j];
  __syncthreads();
  if (j >= Nc) return;
  float acc = bias[j];
  const float4* wr = (const float4*)&W[(size_t)j * K];
  for (int k4 = 0; k4 < K / 4; k4++) {
    float4 wv = wr[k4];
    float4 av = *(const float4*)&arow[k4 * 4];
    acc += av.x * wv.x + av.y * wv.y + av.z * wv.z + av.w * wv.w;
  }
  if (relu) acc = fmaxf(acc, 0.f);
  C[(size_t)g * Nc + j] = acc;
}

__global__ void residual_kernel(const float* __restrict__ r1, const float* __restrict__ Wr2,
                                const float* __restrict__ br2, float* __restrict__ out) {
  int g = threadIdx.x;
  if (g < NGRAPH) {
    float acc = br2[0];
    for (int k = 0; k < 128; k++) acc += r1[(size_t)g * 128 + k] * Wr2[k];
    out[g] = tanhf(acc);
  }
}

// ---------------- launcher ----------------
extern "C" void kernel_launch(void* const* d_in, const int* in_sizes, int n_in,
                              void* d_out, int out_size, void* d_ws, size_t ws_size,
                              hipStream_t stream) {
  const float* x_in   = (const float*)d_in[0];
  const int*   eidx   = (const int*)d_in[1];
  const int*   batch  = (const int*)d_in[2];
  const float* W_in   = (const float*)d_in[3];
  const float* b_in   = (const float*)d_in[4];
  const float* Wl     = (const float*)d_in[5];
  const float* bl     = (const float*)d_in[6];
  const float* Wr     = (const float*)d_in[7];
  const float* br     = (const float*)d_in[8];
  const float* att    = (const float*)d_in[9];
  const float* bias_c = (const float*)d_in[10];
  const float* ln_g   = (const float*)d_in[11];
  const float* ln_b   = (const float*)d_in[12];
  const float* Wg1    = (const float*)d_in[13];
  const float* bg1    = (const float*)d_in[14];
  const float* Wg2    = (const float*)d_in[15];
  const float* bg2    = (const float*)d_in[16];
  const float* Ws     = (const float*)d_in[17];
  const float* bs     = (const float*)d_in[18];
  const float* Wc     = (const float*)d_in[19];
  const float* bc     = (const float*)d_in[20];
  const float* Wr1    = (const float*)d_in[21];
  const float* br1    = (const float*)d_in[22];
  const float* Wr2    = (const float*)d_in[23];
  const float* br2    = (const float*)d_in[24];
  float* out = (float*)d_out;

  char* w = (char*)d_ws;
  float* x    = (float*)w;  w += sizeof(float) * (size_t)N_NODES * H;
  u16* x_bf   = (u16*)w;    w += sizeof(u16) * (size_t)N_NODES * H;
  u16* xl_bf  = (u16*)w;    w += sizeof(u16) * (size_t)N_NODES * H;
  u16* xr_bf  = (u16*)w;    w += sizeof(u16) * (size_t)N_NODES * H;
  u16* xin_bf = (u16*)w;    w += sizeof(u16) * (size_t)N_NODES * IN_DIM;
  u16* win_bf = (u16*)w;    w += sizeof(u16) * (size_t)H * IN_DIM;
  u16* wl_bf  = (u16*)w;    w += sizeof(u16) * (size_t)LAYERS * H * H;
  u16* wr_bf  = (u16*)w;    w += sizeof(u16) * (size_t)LAYERS * H * H;
  u16* wg1_bf = (u16*)w;    w += sizeof(u16) * (size_t)H * H;
  float* pooled = (float*)w; w += sizeof(float) * NGRAPH * H;
  float* z      = (float*)w; w += sizeof(float) * NGRAPH * H;
  float* r1     = (float*)w; w += sizeof(float) * NGRAPH * 128;
  float* gate = (float*)w;  w += sizeof(float) * N_NODES;
  float* gmax = (float*)w;  w += sizeof(float) * NGRAPH;
  float* gdinv= (float*)w;  w += sizeof(float) * NGRAPH;
  int* cnt    = (int*)w;    w += sizeof(int) * N_NODES;
  int* rowp   = (int*)w;    w += sizeof(int) * (N_NODES + 1);
  int* col    = (int*)w;    w += sizeof(int) * EE;
  int* partial= (int*)w;    w += sizeof(int) * N_NODES;
  int* bsums  = (int*)w;    w += sizeof(int) * 256;
  int* gstart = (int*)w;    w += sizeof(int) * NGRAPH;
  int* gend   = (int*)w;    w += sizeof(int) * NGRAPH;
  (void)ws_size; (void)n_in; (void)in_sizes; (void)out_size;

  const int* src = eidx;
  const int* dst = eidx + N_EDGES;
  int nblkN = (N_NODES + 255) / 256;
  int nblkE = (N_EDGES + 255) / 256;

  // CSR build (by dst, self-loops included)
  init_counts_kernel<<<nblkN, 256, 0, stream>>>(cnt);
  count_edges_kernel<<<nblkE, 256, 0, stream>>>(dst, cnt);
  scan_blocks_kernel<<<nblkN, 256, 0, stream>>>(cnt, partial, bsums, N_NODES);
  scan_sums_kernel<<<1, 256, 0, stream>>>(bsums, nblkN);
  scan_write_kernel<<<nblkN, 256, 0, stream>>>(partial, bsums, rowp, N_NODES);
  fill_self_kernel<<<nblkN, 256, 0, stream>>>(rowp, col, cnt);
  fill_edges_kernel<<<nblkE, 256, 0, stream>>>(src, dst, cnt, col);

  // casts
  auto cast = [&](const float* src_f, u16* dst_b, int n) {
    int n4 = n / 4;
    cast_bf16_kernel<<<(n4 + 255) / 256, 256, 0, stream>>>(src_f, dst_b, n4);
  };
  cast(W_in, win_bf, H * IN_DIM);
  cast(Wl, wl_bf, LAYERS * H * H);
  cast(Wr, wr_bf, LAYERS * H * H);
  cast(Wg1, wg1_bf, H * H);
  cast(x_in, xin_bf, N_NODES * IN_DIM);

  // input projection
  dim3 gproj(H / GTN, (N_NODES + GTM - 1) / GTM);
  gemm_mfma_kernel<<<gproj, 256, 0, stream>>>(xin_bf, win_bf, b_in, x, x_bf, N_NODES, IN_DIM);

  int nblkV = N_NODES / 4;
  dim3 gdual(2 * H / GTN, (N_NODES + GTM - 1) / GTM);
  for (int l = 0; l < LAYERS; l++) {
    gemm_mfma_dual_kernel<<<gdual, 256, 0, stream>>>(x_bf,
        wl_bf + (size_t)l * H * H, wr_bf + (size_t)l * H * H,
        bl + l * H, br + l * H, xl_bf, xr_bf, N_NODES);
    layer_fused_kernel<<<nblkV, 256, 0, stream>>>(xl_bf, xr_bf, x, x_bf, rowp, col,
        att + l * H, bias_c + l * H, ln_g + l * H, ln_b + l * H);
  }

  // gate (fused GEMM + row-dot)
  gate_init_kernel<<<nblkN, 256, 0, stream>>>(gate, bg2);
  dim3 ggate(H / GTN, (N_NODES + GTM - 1) / GTM);
  gemm_gate_kernel<<<ggate, 256, 0, stream>>>(x_bf, wg1_bf, bg1, Wg2, gate, N_NODES);

  // pooling
  ginit_kernel<<<1, 64, 0, stream>>>(gstart, gend);
  gbounds_kernel<<<nblkN, 256, 0, stream>>>(batch, gstart, gend);
  pool_prep_kernel<<<NGRAPH, 256, 0, stream>>>(gate, gstart, gend, gmax, gdinv);
  pool_zero_kernel<<<(NGRAPH * H + 255) / 256, 256, 0, stream>>>(pooled);
  pool_accum_kernel<<<(N_NODES + 127) / 128, 256, 0, stream>>>(gate, x, batch, gmax, gdinv, pooled);

  // heads
  small_gemm_kernel<<<NGRAPH, 256, 0, stream>>>(pooled, Ws, bs, z, H, H, 1);
  small_gemm_kernel<<<NGRAPH, 256, 0, stream>>>(z, Wc, bc, out, H, NB, 0);
  small_gemm_kernel<<<NGRAPH, 256, 0, stream>>>(z, Wr1, br1, r1, H, 128, 1);
  residual_kernel<<<1, 64, 0, stream>>>(r1, Wr2, br2, out + (size_t)NGRAPH * NB);
}

// Round 5
// 746.080 us; speedup vs baseline: 2.3986x; 1.0461x over previous
//
#include <hip/hip_runtime.h>
#include <math.h>

#define N_NODES 50000
#define N_EDGES 300000
#define IN_DIM 64
#define H 256
#define LAYERS 4
#define NB 181
#define NGRAPH 64
#define EE (N_EDGES + N_NODES)
#define NEG_SLOPE 0.2f
#define LN_EPS 1e-5f

typedef unsigned short u16;
typedef __attribute__((ext_vector_type(8))) short short8;
typedef __attribute__((ext_vector_type(4))) float floatx4;

__device__ __forceinline__ u16 f2b(float f) {
  unsigned int u = __builtin_bit_cast(unsigned int, f);
  unsigned int r = (u + 0x7FFFu + ((u >> 16) & 1u)) >> 16;
  return (u16)r;
}
__device__ __forceinline__ float b2f(u16 b) {
  return __builtin_bit_cast(float, ((unsigned int)b) << 16);
}

__device__ __forceinline__ float wave_reduce_sum(float v) {
  #pragma unroll
  for (int off = 32; off > 0; off >>= 1) v += __shfl_xor(v, off, 64);
  return v;
}

// ---------------- cast fp32 -> bf16 ----------------
__global__ void cast_bf16_kernel(const float* __restrict__ in, u16* __restrict__ out, int n4) {
  int i = blockIdx.x * 256 + threadIdx.x;
  if (i < n4) {
    float4 f = ((const float4*)in)[i];
    ushort4 o;
    o.x = f2b(f.x); o.y = f2b(f.y); o.z = f2b(f.z); o.w = f2b(f.w);
    ((ushort4*)out)[i] = o;
  }
}

// ---------------- CSR build ----------------
__global__ void init_counts_kernel(int* __restrict__ cnt) {
  int i = blockIdx.x * 256 + threadIdx.x;
  if (i < N_NODES) cnt[i] = 1;  // self loop
}

__global__ void count_edges_kernel(const int* __restrict__ dst, int* __restrict__ cnt) {
  int e = blockIdx.x * 256 + threadIdx.x;
  if (e < N_EDGES) atomicAdd(&cnt[dst[e]], 1);
}

__global__ void scan_blocks_kernel(const int* __restrict__ cnt, int* __restrict__ partial,
                                   int* __restrict__ bsums, int n) {
  __shared__ int buf[256];
  int tid = threadIdx.x;
  int i = blockIdx.x * 256 + tid;
  buf[tid] = (i < n) ? cnt[i] : 0;
  __syncthreads();
  #pragma unroll
  for (int off = 1; off < 256; off <<= 1) {
    int t = (tid >= off) ? buf[tid - off] : 0;
    __syncthreads();
    buf[tid] += t;
    __syncthreads();
  }
  if (i < n) partial[i] = buf[tid];
  if (tid == 255) bsums[blockIdx.x] = buf[255];
}

__global__ void scan_sums_kernel(int* __restrict__ bsums, int nblk) {
  __shared__ int buf[256];
  int tid = threadIdx.x;
  buf[tid] = (tid < nblk) ? bsums[tid] : 0;
  __syncthreads();
  #pragma unroll
  for (int off = 1; off < 256; off <<= 1) {
    int t = (tid >= off) ? buf[tid - off] : 0;
    __syncthreads();
    buf[tid] += t;
    __syncthreads();
  }
  if (tid < nblk) bsums[tid] = buf[tid];
}

__global__ void scan_write_kernel(const int* __restrict__ partial, const int* __restrict__ bsums,
                                  int* __restrict__ rowp, int n) {
  int i = blockIdx.x * 256 + threadIdx.x;
  if (i < n) {
    int b = blockIdx.x;
    int off = (b > 0) ? bsums[b - 1] : 0;
    rowp[i + 1] = partial[i] + off;
    if (i == 0) rowp[0] = 0;
  }
}

__global__ void fill_self_kernel(const int* __restrict__ rowp, int* __restrict__ col,
                                 int* __restrict__ fillpos) {
  int i = blockIdx.x * 256 + threadIdx.x;
  if (i < N_NODES) {
    int p = rowp[i];
    col[p] = i;
    fillpos[i] = p + 1;
  }
}

__global__ void fill_edges_kernel(const int* __restrict__ src, const int* __restrict__ dst,
                                  int* __restrict__ fillpos, int* __restrict__ col) {
  int e = blockIdx.x * 256 + threadIdx.x;
  if (e < N_EDGES) {
    int d = dst[e];
    int p = atomicAdd(&fillpos[d], 1);
    col[p] = src[e];
  }
}

// ---------------- MFMA GEMM tiles ----------------
#define GTM 128
#define GTK 64
#define LDB 72
#define SSTR 132  // stage stride in u16: 264 B rows, 2-way-max LDS banks on b64 copy

// input projection: out_bf[M,256] = A[M,K]@W^T + bias (bf16 out, staged coalesced)
__global__ __launch_bounds__(256) void gemm_proj_kernel(
    const u16* __restrict__ A, const u16* __restrict__ W,
    const float* __restrict__ bias, u16* __restrict__ outbf, int M, int K)
{
  __shared__ u16 smem[2 * GTM * LDB];
  u16* As = smem;
  u16* Bs = smem + GTM * LDB;
  int tid = threadIdx.x;
  int lane = tid & 63;
  int wave = tid >> 6;
  int wm = (wave >> 1) * 64;
  int wn = (wave & 1) * 64;
  int bm = blockIdx.y * GTM;
  int n0 = blockIdx.x * 128;
  int lr = tid >> 3;
  int lc = (tid & 7) * 8;

  floatx4 zero4 = {0.f, 0.f, 0.f, 0.f};
  floatx4 acc[4][4];
  #pragma unroll
  for (int i = 0; i < 4; i++)
    #pragma unroll
    for (int j = 0; j < 4; j++) acc[i][j] = zero4;

  int q8 = (lane >> 4) * 8;
  int mrow = lane & 15;

  for (int k0 = 0; k0 < K; k0 += GTK) {
    __syncthreads();
    #pragma unroll
    for (int p = 0; p < 4; p++) {
      int row = lr + p * 32;
      int gr = bm + row;
      short8 av = {0, 0, 0, 0, 0, 0, 0, 0};
      if (gr < M) av = *(const short8*)&A[(size_t)gr * K + k0 + lc];
      *(short8*)&As[row * LDB + lc] = av;
      short8 bv = *(const short8*)&W[(size_t)(n0 + row) * K + k0 + lc];
      *(short8*)&Bs[row * LDB + lc] = bv;
    }
    __syncthreads();
    #pragma unroll
    for (int h = 0; h < 2; h++) {
      short8 af[4], bf[4];
      #pragma unroll
      for (int i = 0; i < 4; i++)
        af[i] = *(const short8*)&As[(wm + i * 16 + mrow) * LDB + h * 32 + q8];
      #pragma unroll
      for (int j = 0; j < 4; j++)
        bf[j] = *(const short8*)&Bs[(wn + j * 16 + mrow) * LDB + h * 32 + q8];
      #pragma unroll
      for (int i = 0; i < 4; i++)
        #pragma unroll
        for (int j = 0; j < 4; j++)
          acc[i][j] = __builtin_amdgcn_mfma_f32_16x16x32_bf16(af[i], bf[j], acc[i][j], 0, 0, 0);
    }
  }

  // staged coalesced epilogue
  __syncthreads();
  u16* stage = smem;
  int ccol = lane & 15;
  int crow4 = (lane >> 4) * 4;
  #pragma unroll
  for (int j = 0; j < 4; j++) {
    float bv = bias[n0 + wn + j * 16 + ccol];
    #pragma unroll
    for (int i = 0; i < 4; i++) {
      #pragma unroll
      for (int r = 0; r < 4; r++) {
        int row = wm + i * 16 + crow4 + r;
        stage[row * SSTR + wn + j * 16 + ccol] = f2b(acc[i][j][r] + bv);
      }
    }
  }
  __syncthreads();
  int rr = tid >> 1;
  int c0 = (tid & 1) * 64;
  int grow = bm + rr;
  if (grow < M) {
    const ushort4* sp = (const ushort4*)&stage[rr * SSTR + c0];
    ushort4* gp = (ushort4*)&outbf[(size_t)grow * H + n0 + c0];
    #pragma unroll
    for (int q = 0; q < 16; q++) gp[q] = sp[q];
  }
}

// dual GEMM: per m-tile block, loop 4 n-tiles (Wl cols 0..255, Wr cols 0..255)
// A tile stays L2-resident across the n-loop; staged coalesced bf16 epilogue.
__global__ __launch_bounds__(256) void gemm_mfma_dual_kernel(
    const u16* __restrict__ A, const u16* __restrict__ Wlb, const u16* __restrict__ Wrb,
    const float* __restrict__ biasL, const float* __restrict__ biasR,
    u16* __restrict__ outL, u16* __restrict__ outR, int M)
{
  __shared__ u16 smem[2 * GTM * LDB];
  u16* As = smem;
  u16* Bs = smem + GTM * LDB;
  int tid = threadIdx.x;
  int lane = tid & 63;
  int wave = tid >> 6;
  int wm = (wave >> 1) * 64;
  int wn = (wave & 1) * 64;
  int bm = blockIdx.x * GTM;
  int lr = tid >> 3;
  int lc = (tid & 7) * 8;
  int q8 = (lane >> 4) * 8;
  int mrow = lane & 15;
  int ccol = lane & 15;
  int crow4 = (lane >> 4) * 4;
  int rr = tid >> 1;
  int c0 = (tid & 1) * 64;
  int grow = bm + rr;

  floatx4 zero4 = {0.f, 0.f, 0.f, 0.f};

  for (int nt = 0; nt < 4; nt++) {
    const u16* W = (nt < 2) ? Wlb : Wrb;
    const float* bias = (nt < 2) ? biasL : biasR;
    u16* outp = (nt < 2) ? outL : outR;
    int n0 = (nt & 1) * 128;

    floatx4 acc[4][4];
    #pragma unroll
    for (int i = 0; i < 4; i++)
      #pragma unroll
      for (int j = 0; j < 4; j++) acc[i][j] = zero4;

    for (int k0 = 0; k0 < H; k0 += GTK) {
      __syncthreads();
      #pragma unroll
      for (int p = 0; p < 4; p++) {
        int row = lr + p * 32;
        int gr = bm + row;
        short8 av = {0, 0, 0, 0, 0, 0, 0, 0};
        if (gr < M) av = *(const short8*)&A[(size_t)gr * H + k0 + lc];
        *(short8*)&As[row * LDB + lc] = av;
        short8 bv = *(const short8*)&W[(size_t)(n0 + row) * H + k0 + lc];
        *(short8*)&Bs[row * LDB + lc] = bv;
      }
      __syncthreads();
      #pragma unroll
      for (int h = 0; h < 2; h++) {
        short8 af[4], bf[4];
        #pragma unroll
        for (int i = 0; i < 4; i++)
          af[i] = *(const short8*)&As[(wm + i * 16 + mrow) * LDB + h * 32 + q8];
        #pragma unroll
        for (int j = 0; j < 4; j++)
          bf[j] = *(const short8*)&Bs[(wn + j * 16 + mrow) * LDB + h * 32 + q8];
        #pragma unroll
        for (int i = 0; i < 4; i++)
          #pragma unroll
          for (int j = 0; j < 4; j++)
            acc[i][j] = __builtin_amdgcn_mfma_f32_16x16x32_bf16(af[i], bf[j], acc[i][j], 0, 0, 0);
      }
    }

    __syncthreads();
    u16* stage = smem;
    #pragma unroll
    for (int j = 0; j < 4; j++) {
      float bv = bias[n0 + wn + j * 16 + ccol];
      #pragma unroll
      for (int i = 0; i < 4; i++) {
        #pragma unroll
        for (int r = 0; r < 4; r++) {
          int row = wm + i * 16 + crow4 + r;
          stage[row * SSTR + wn + j * 16 + ccol] = f2b(acc[i][j][r] + bv);
        }
      }
    }
    __syncthreads();
    if (grow < M) {
      const ushort4* sp = (const ushort4*)&stage[rr * SSTR + c0];
      ushort4* gp = (ushort4*)&outp[(size_t)grow * H + n0 + c0];
      #pragma unroll
      for (int q = 0; q < 16; q++) gp[q] = sp[q];
    }
  }
}

// gate GEMM: gate[row] += sum_col relu(x@Wg1 + bg1)[col] * Wg2[col]; gate pre-init to bg2
__global__ __launch_bounds__(256) void gemm_gate_kernel(
    const u16* __restrict__ A, const u16* __restrict__ W,
    const float* __restrict__ bias, const float* __restrict__ Wg2,
    float* __restrict__ gate, int M)
{
  __shared__ u16 smem[2 * GTM * LDB];
  u16* As = smem;
  u16* Bs = smem + GTM * LDB;
  int tid = threadIdx.x;
  int lane = tid & 63;
  int wave = tid >> 6;
  int wm = (wave >> 1) * 64;
  int wn = (wave & 1) * 64;
  int bm = blockIdx.y * GTM;
  int bn = blockIdx.x * 128;
  int lr = tid >> 3;
  int lc = (tid & 7) * 8;

  floatx4 zero4 = {0.f, 0.f, 0.f, 0.f};
  floatx4 acc[4][4];
  #pragma unroll
  for (int i = 0; i < 4; i++)
    #pragma unroll
    for (int j = 0; j < 4; j++) acc[i][j] = zero4;

  int q8 = (lane >> 4) * 8;
  int mrow = lane & 15;

  for (int k0 = 0; k0 < H; k0 += GTK) {
    __syncthreads();
    #pragma unroll
    for (int p = 0; p < 4; p++) {
      int row = lr + p * 32;
      int gr = bm + row;
      short8 av = {0, 0, 0, 0, 0, 0, 0, 0};
      if (gr < M) av = *(const short8*)&A[(size_t)gr * H + k0 + lc];
      *(short8*)&As[row * LDB + lc] = av;
      short8 bv = *(const short8*)&W[(size_t)(bn + row) * H + k0 + lc];
      *(short8*)&Bs[row * LDB + lc] = bv;
    }
    __syncthreads();
    #pragma unroll
    for (int h = 0; h < 2; h++) {
      short8 af[4], bf[4];
      #pragma unroll
      for (int i = 0; i < 4; i++)
        af[i] = *(const short8*)&As[(wm + i * 16 + mrow) * LDB + h * 32 + q8];
      #pragma unroll
      for (int j = 0; j < 4; j++)
        bf[j] = *(const short8*)&Bs[(wn + j * 16 + mrow) * LDB + h * 32 + q8];
      #pragma unroll
      for (int i = 0; i < 4; i++)
        #pragma unroll
        for (int j = 0; j < 4; j++)
          acc[i][j] = __builtin_amdgcn_mfma_f32_16x16x32_bf16(af[i], bf[j], acc[i][j], 0, 0, 0);
    }
  }

  int ccol = lane & 15;
  float bv[4], wv[4];
  #pragma unroll
  for (int j = 0; j < 4; j++) {
    int col = bn + wn + j * 16 + ccol;
    bv[j] = bias[col];
    wv[j] = Wg2[col];
  }
  #pragma unroll
  for (int i = 0; i < 4; i++) {
    #pragma unroll
    for (int r = 0; r < 4; r++) {
      float p = 0.f;
      #pragma unroll
      for (int j = 0; j < 4; j++) {
        float hcol = fmaxf(acc[i][j][r] + bv[j], 0.f);
        p += hcol * wv[j];
      }
      p += __shfl_xor(p, 1, 64);
      p += __shfl_xor(p, 2, 64);
      p += __shfl_xor(p, 4, 64);
      p += __shfl_xor(p, 8, 64);
      int row = bm + wm + i * 16 + (lane >> 4) * 4 + r;
      if ((lane & 15) == 0 && row < M) atomicAdd(&gate[row], p);
    }
  }
}

// ---------------- fused edge softmax + aggregate + LN + residual (all bf16 state) ----------------
__global__ __launch_bounds__(256) void layer_fused_kernel(
    const u16* __restrict__ xl, const u16* __restrict__ xr,
    u16* __restrict__ xbf,
    const int* __restrict__ rowp, const int* __restrict__ col,
    const float* __restrict__ att, const float* __restrict__ bias_c,
    const float* __restrict__ ln_g, const float* __restrict__ ln_b)
{
  int lane = threadIdx.x & 63;
  int v = blockIdx.x * 4 + (threadIdx.x >> 6);
  if (v >= N_NODES) return;
  int f4 = lane << 2;
  size_t rowbase = (size_t)v * H;
  ushort4 xr4 = *(const ushort4*)&xr[rowbase + f4];
  float4 xrv = make_float4(b2f(xr4.x), b2f(xr4.y), b2f(xr4.z), b2f(xr4.w));
  float4 attv = *(const float4*)&att[f4];
  int beg = rowp[v], end = rowp[v + 1];
  float m = -INFINITY, d = 0.0f;
  float4 o = make_float4(0.f, 0.f, 0.f, 0.f);
  for (int p = beg; p < end; p++) {
    int u = col[p];
    ushort4 a4 = *(const ushort4*)&xl[(size_t)u * H + f4];
    float ax = b2f(a4.x), ay = b2f(a4.y), az = b2f(a4.z), aw = b2f(a4.w);
    float tx = ax + xrv.x, ty = ay + xrv.y, tz = az + xrv.z, tw = aw + xrv.w;
    tx = tx > 0.f ? tx : NEG_SLOPE * tx;
    ty = ty > 0.f ? ty : NEG_SLOPE * ty;
    tz = tz > 0.f ? tz : NEG_SLOPE * tz;
    tw = tw > 0.f ? tw : NEG_SLOPE * tw;
    float pe = tx * attv.x + ty * attv.y + tz * attv.z + tw * attv.w;
    pe = wave_reduce_sum(pe);
    // wave-uniform branch: rescale only when a new max appears
    if (pe > m) {
      float sc = __expf(m - pe);  // exp(-inf)=0 on first edge
      d = d * sc + 1.0f;
      o.x = o.x * sc + ax;
      o.y = o.y * sc + ay;
      o.z = o.z * sc + az;
      o.w = o.w * sc + aw;
      m = pe;
    } else {
      float wgt = __expf(pe - m);
      d += wgt;
      o.x = fmaf(wgt, ax, o.x);
      o.y = fmaf(wgt, ay, o.y);
      o.z = fmaf(wgt, az, o.z);
      o.w = fmaf(wgt, aw, o.w);
    }
  }
  float invd = 1.0f / d;
  float4 bc4 = *(const float4*)&bias_c[f4];
  float ox = o.x * invd + bc4.x;
  float oy = o.y * invd + bc4.y;
  float oz = o.z * invd + bc4.z;
  float ow = o.w * invd + bc4.w;
  float s = wave_reduce_sum(ox + oy + oz + ow);
  float mean = s * (1.0f / H);
  float cx = ox - mean, cy = oy - mean, cz = oz - mean, cw = ow - mean;
  float sq = wave_reduce_sum(cx * cx + cy * cy + cz * cz + cw * cw);
  float rstd = rsqrtf(sq * (1.0f / H) + LN_EPS);
  float4 g4 = *(const float4*)&ln_g[f4];
  float4 b4 = *(const float4*)&ln_b[f4];
  ushort4 xres4 = *(const ushort4*)&xbf[rowbase + f4];
  float4 y;
  y.x = fmaxf(cx * rstd * g4.x + b4.x, 0.f) + b2f(xres4.x);
  y.y = fmaxf(cy * rstd * g4.y + b4.y, 0.f) + b2f(xres4.y);
  y.z = fmaxf(cz * rstd * g4.z + b4.z, 0.f) + b2f(xres4.z);
  y.w = fmaxf(cw * rstd * g4.w + b4.w, 0.f) + b2f(xres4.w);
  ushort4 yb;
  yb.x = f2b(y.x); yb.y = f2b(y.y); yb.z = f2b(y.z); yb.w = f2b(y.w);
  *(ushort4*)&xbf[rowbase + f4] = yb;
}

// ---------------- gate init ----------------
__global__ void gate_init_kernel(float* __restrict__ gate, const float* __restrict__ bg2) {
  int i = blockIdx.x * 256 + threadIdx.x;
  if (i < N_NODES) gate[i] = bg2[0];
}

// ---------------- graph bounds (sorted batch) ----------------
__global__ void ginit_kernel(int* __restrict__ gstart, int* __restrict__ gend) {
  int t = threadIdx.x;
  if (t < NGRAPH) { gstart[t] = N_NODES; gend[t] = 0; }
}

__global__ void gbounds_kernel(const int* __restrict__ batch, int* __restrict__ gstart,
                               int* __restrict__ gend) {
  int i = blockIdx.x * 256 + threadIdx.x;
  if (i < N_NODES) {
    int b = batch[i];
    if (i == 0 || batch[i - 1] != b) gstart[b] = i;
    if (i == N_NODES - 1 || batch[i + 1] != b) gend[b] = i + 1;
  }
}

// ---------------- pooling: per-graph softmax stats ----------------
__global__ __launch_bounds__(256) void pool_prep_kernel(
    const float* __restrict__ gate, const int* __restrict__ gstart,
    const int* __restrict__ gend, float* __restrict__ gmax, float* __restrict__ gdinv)
{
  __shared__ float red[256];
  int g = blockIdx.x, tid = threadIdx.x;
  int s = gstart[g], e = gend[g];
  float lm = -INFINITY;
  for (int i = s + tid; i < e; i += 256) lm = fmaxf(lm, gate[i]);
  red[tid] = lm;
  __syncthreads();
  for (int off = 128; off; off >>= 1) {
    if (tid < off) red[tid] = fmaxf(red[tid], red[tid + off]);
    __syncthreads();
  }
  float m = red[0];
  __syncthreads();
  float lsum = 0.0f;
  for (int i = s + tid; i < e; i += 256) lsum += __expf(gate[i] - m);
  red[tid] = lsum;
  __syncthreads();
  for (int off = 128; off; off >>= 1) {
    if (tid < off) red[tid] += red[tid + off];
    __syncthreads();
  }
  if (tid == 0) {
    gmax[g] = m;
    gdinv[g] = (s < e) ? 1.0f / red[0] : 0.0f;
  }
}

// ---------------- pooled zero init ----------------
__global__ void pool_zero_kernel(float* __restrict__ pooled) {
  int i = blockIdx.x * 256 + threadIdx.x;
  if (i < NGRAPH * H) pooled[i] = 0.f;
}

// ---------------- pooling: weighted accumulate (128 nodes per block, bf16 x) ----------------
__global__ __launch_bounds__(256) void pool_accum_kernel(
    const float* __restrict__ gate, const u16* __restrict__ xbf,
    const int* __restrict__ batch, const float* __restrict__ gmax,
    const float* __restrict__ gdinv, float* __restrict__ pooled)
{
  __shared__ float wl[128];
  __shared__ int gl[128];
  int b0 = blockIdx.x * 128;
  int tid = threadIdx.x;
  if (tid < 128) {
    int v = b0 + tid;
    if (v < N_NODES) {
      int g = batch[v];
      gl[tid] = g;
      wl[tid] = __expf(gate[v] - gmax[g]) * gdinv[g];
    } else {
      gl[tid] = -1;
      wl[tid] = 0.f;
    }
  }
  __syncthreads();
  int cnt = min(128, N_NODES - b0);
  float acc = 0.f;
  int cur = gl[0];
  for (int j = 0; j < cnt; j++) {
    int g = gl[j];
    if (g != cur) {
      atomicAdd(&pooled[(size_t)cur * H + tid], acc);
      acc = 0.f;
      cur = g;
    }
    acc += wl[j] * b2f(xbf[(size_t)(b0 + j) * H + tid]);
  }
  if (cur >= 0) atomicAdd(&pooled[(size_t)cur * H + tid], acc);
}

// ---------------- small GEMM (G rows) ----------------
__global__ __launch_bounds__(256) void small_gemm_kernel(
    const float* __restrict__ A, const float* __restrict__ W,
    const float* __restrict__ bias, float* __restrict__ C,
    int K, int Nc, int relu)
{
  __shared__ float arow[256];
  int g = blockIdx.x, j = threadIdx.x;
  if (j < K) arow[j] = A[(size_t)g * K + j];
  __syncthreads();
  if (j >= Nc) return;
  float acc = bias[j];
  const float4* wr = (const float4*)&W[(size_t)j * K];
  for (int k4 = 0; k4 < K / 4; k4++) {
    float4 wv = wr[k4];
    float4 av = *(const float4*)&arow[k4 * 4];
    acc += av.x * wv.x + av.y * wv.y + av.z * wv.z + av.w * wv.w;
  }
  if (relu) acc = fmaxf(acc, 0.f);
  C[(size_t)g * Nc + j] = acc;
}

__global__ void residual_kernel(const float* __restrict__ r1, const float* __restrict__ Wr2,
                                const float* __restrict__ br2, float* __restrict__ out) {
  int g = threadIdx.x;
  if (g < NGRAPH) {
    float acc = br2[0];
    for (int k = 0; k < 128; k++) acc += r1[(size_t)g * 128 + k] * Wr2[k];
    out[g] = tanhf(acc);
  }
}

// ---------------- launcher ----------------
extern "C" void kernel_launch(void* const* d_in, const int* in_sizes, int n_in,
                              void* d_out, int out_size, void* d_ws, size_t ws_size,
                              hipStream_t stream) {
  const float* x_in   = (const float*)d_in[0];
  const int*   eidx   = (const int*)d_in[1];
  const int*   batch  = (const int*)d_in[2];
  const float* W_in   = (const float*)d_in[3];
  const float* b_in   = (const float*)d_in[4];
  const float* Wl     = (const float*)d_in[5];
  const float* bl     = (const float*)d_in[6];
  const float* Wr     = (const float*)d_in[7];
  const float* br     = (const float*)d_in[8];
  const float* att    = (const float*)d_in[9];
  const float* bias_c = (const float*)d_in[10];
  const float* ln_g   = (const float*)d_in[11];
  const float* ln_b   = (const float*)d_in[12];
  const float* Wg1    = (const float*)d_in[13];
  const float* bg1    = (const float*)d_in[14];
  const float* Wg2    = (const float*)d_in[15];
  const float* bg2    = (const float*)d_in[16];
  const float* Ws     = (const float*)d_in[17];
  const float* bs     = (const float*)d_in[18];
  const float* Wc     = (const float*)d_in[19];
  const float* bc     = (const float*)d_in[20];
  const float* Wr1    = (const float*)d_in[21];
  const float* br1    = (const float*)d_in[22];
  const float* Wr2    = (const float*)d_in[23];
  const float* br2    = (const float*)d_in[24];
  float* out = (float*)d_out;

  char* w = (char*)d_ws;
  u16* x_bf   = (u16*)w;    w += sizeof(u16) * (size_t)N_NODES * H;
  u16* xl_bf  = (u16*)w;    w += sizeof(u16) * (size_t)N_NODES * H;
  u16* xr_bf  = (u16*)w;    w += sizeof(u16) * (size_t)N_NODES * H;
  u16* xin_bf = (u16*)w;    w += sizeof(u16) * (size_t)N_NODES * IN_DIM;
  u16* win_bf = (u16*)w;    w += sizeof(u16) * (size_t)H * IN_DIM;
  u16* wl_bf  = (u16*)w;    w += sizeof(u16) * (size_t)LAYERS * H * H;
  u16* wr_bf  = (u16*)w;    w += sizeof(u16) * (size_t)LAYERS * H * H;
  u16* wg1_bf = (u16*)w;    w += sizeof(u16) * (size_t)H * H;
  float* pooled = (float*)w; w += sizeof(float) * NGRAPH * H;
  float* z      = (float*)w; w += sizeof(float) * NGRAPH * H;
  float* r1     = (float*)w; w += sizeof(float) * NGRAPH * 128;
  float* gate = (float*)w;  w += sizeof(float) * N_NODES;
  float* gmax = (float*)w;  w += sizeof(float) * NGRAPH;
  float* gdinv= (float*)w;  w += sizeof(float) * NGRAPH;
  int* cnt    = (int*)w;    w += sizeof(int) * N_NODES;
  int* rowp   = (int*)w;    w += sizeof(int) * (N_NODES + 1);
  int* col    = (int*)w;    w += sizeof(int) * EE;
  int* partial= (int*)w;    w += sizeof(int) * N_NODES;
  int* bsums  = (int*)w;    w += sizeof(int) * 256;
  int* gstart = (int*)w;    w += sizeof(int) * NGRAPH;
  int* gend   = (int*)w;    w += sizeof(int) * NGRAPH;
  (void)ws_size; (void)n_in; (void)in_sizes; (void)out_size;

  const int* src = eidx;
  const int* dst = eidx + N_EDGES;
  int nblkN = (N_NODES + 255) / 256;
  int nblkE = (N_EDGES + 255) / 256;
  int mtiles = (N_NODES + GTM - 1) / GTM;

  // CSR build (by dst, self-loops included)
  init_counts_kernel<<<nblkN, 256, 0, stream>>>(cnt);
  count_edges_kernel<<<nblkE, 256, 0, stream>>>(dst, cnt);
  scan_blocks_kernel<<<nblkN, 256, 0, stream>>>(cnt, partial, bsums, N_NODES);
  scan_sums_kernel<<<1, 256, 0, stream>>>(bsums, nblkN);
  scan_write_kernel<<<nblkN, 256, 0, stream>>>(partial, bsums, rowp, N_NODES);
  fill_self_kernel<<<nblkN, 256, 0, stream>>>(rowp, col, cnt);
  fill_edges_kernel<<<nblkE, 256, 0, stream>>>(src, dst, cnt, col);

  // casts
  auto cast = [&](const float* src_f, u16* dst_b, int n) {
    int n4 = n / 4;
    cast_bf16_kernel<<<(n4 + 255) / 256, 256, 0, stream>>>(src_f, dst_b, n4);
  };
  cast(W_in, win_bf, H * IN_DIM);
  cast(Wl, wl_bf, LAYERS * H * H);
  cast(Wr, wr_bf, LAYERS * H * H);
  cast(Wg1, wg1_bf, H * H);
  cast(x_in, xin_bf, N_NODES * IN_DIM);

  // input projection -> x_bf
  dim3 gproj(2, mtiles);
  gemm_proj_kernel<<<gproj, 256, 0, stream>>>(xin_bf, win_bf, b_in, x_bf, N_NODES, IN_DIM);

  int nblkV = N_NODES / 4;
  for (int l = 0; l < LAYERS; l++) {
    gemm_mfma_dual_kernel<<<mtiles, 256, 0, stream>>>(x_bf,
        wl_bf + (size_t)l * H * H, wr_bf + (size_t)l * H * H,
        bl + l * H, br + l * H, xl_bf, xr_bf, N_NODES);
    layer_fused_kernel<<<nblkV, 256, 0, stream>>>(xl_bf, xr_bf, x_bf, rowp, col,
        att + l * H, bias_c + l * H, ln_g + l * H, ln_b + l * H);
  }

  // gate (fused GEMM + row-dot)
  gate_init_kernel<<<nblkN, 256, 0, stream>>>(gate, bg2);
  dim3 ggate(2, mtiles);
  gemm_gate_kernel<<<ggate, 256, 0, stream>>>(x_bf, wg1_bf, bg1, Wg2, gate, N_NODES);

  // pooling
  ginit_kernel<<<1, 64, 0, stream>>>(gstart, gend);
  gbounds_kernel<<<nblkN, 256, 0, stream>>>(batch, gstart, gend);
  pool_prep_kernel<<<NGRAPH, 256, 0, stream>>>(gate, gstart, gend, gmax, gdinv);
  pool_zero_kernel<<<(NGRAPH * H + 255) / 256, 256, 0, stream>>>(pooled);
  pool_accum_kernel<<<(N_NODES + 127) / 128, 256, 0, stream>>>(gate, x_bf, batch, gmax, gdinv, pooled);

  // heads
  small_gemm_kernel<<<NGRAPH, 256, 0, stream>>>(pooled, Ws, bs, z, H, H, 1);
  small_gemm_kernel<<<NGRAPH, 256, 0, stream>>>(z, Wc, bc, out, H, NB, 0);
  small_gemm_kernel<<<NGRAPH, 256, 0, stream>>>(z, Wr1, br1, r1, H, 128, 1);
  residual_kernel<<<1, 64, 0, stream>>>(r1, Wr2, br2, out + (size_t)NGRAPH * NB);
}

// Round 6
// 639.673 us; speedup vs baseline: 2.7976x; 1.1663x over previous
//
#include <hip/hip_runtime.h>
#include <math.h>

#define N_NODES 50000
#define N_EDGES 300000
#define IN_DIM 64
#define H 256
#define LAYERS 4
#define NB 181
#define NGRAPH 64
#define EE (N_EDGES + N_NODES)
#define NEG_SLOPE 0.2f
#define LN_EPS 1e-5f

typedef unsigned short u16;
typedef __attribute__((ext_vector_type(8))) short short8;
typedef __attribute__((ext_vector_type(4))) float floatx4;

__device__ __forceinline__ u16 f2b(float f) {
  unsigned int u = __builtin_bit_cast(unsigned int, f);
  unsigned int r = (u + 0x7FFFu + ((u >> 16) & 1u)) >> 16;
  return (u16)r;
}
__device__ __forceinline__ float b2f(u16 b) {
  return __builtin_bit_cast(float, ((unsigned int)b) << 16);
}

__device__ __forceinline__ float wave_reduce_sum(float v) {
  #pragma unroll
  for (int off = 32; off > 0; off >>= 1) v += __shfl_xor(v, off, 64);
  return v;
}

// ---------------- casts ----------------
__global__ void cast_bf16_kernel(const float* __restrict__ in, u16* __restrict__ out, int n4) {
  int i = blockIdx.x * 256 + threadIdx.x;
  if (i < n4) {
    float4 f = ((const float4*)in)[i];
    ushort4 o;
    o.x = f2b(f.x); o.y = f2b(f.y); o.z = f2b(f.z); o.w = f2b(f.w);
    ((ushort4*)out)[i] = o;
  }
}

// all weight casts in one launch (blockIdx.y selects tensor)
__global__ void cast_weights_kernel(
    const float* __restrict__ W_in, const float* __restrict__ Wg1,
    const float* __restrict__ Wl, const float* __restrict__ Wr,
    u16* __restrict__ win_bf, u16* __restrict__ wg1_bf,
    u16* __restrict__ wl_bf, u16* __restrict__ wr_bf)
{
  int i = blockIdx.x * 256 + threadIdx.x;
  int which = blockIdx.y;
  const float* s; u16* dd; int n4;
  if (which == 0)      { s = W_in; dd = win_bf; n4 = H * IN_DIM / 4; }
  else if (which == 1) { s = Wg1;  dd = wg1_bf; n4 = H * H / 4; }
  else if (which == 2) { s = Wl;   dd = wl_bf;  n4 = LAYERS * H * H / 4; }
  else                 { s = Wr;   dd = wr_bf;  n4 = LAYERS * H * H / 4; }
  if (i < n4) {
    float4 f = ((const float4*)s)[i];
    ushort4 o;
    o.x = f2b(f.x); o.y = f2b(f.y); o.z = f2b(f.z); o.w = f2b(f.w);
    ((ushort4*)dd)[i] = o;
  }
}

// ---------------- CSR build ----------------
__global__ void init_counts_kernel(int* __restrict__ cnt) {
  int i = blockIdx.x * 256 + threadIdx.x;
  if (i < N_NODES) cnt[i] = 1;  // self loop
}

__global__ void count_edges_kernel(const int* __restrict__ dst, int* __restrict__ cnt) {
  int e = blockIdx.x * 256 + threadIdx.x;
  if (e < N_EDGES) atomicAdd(&cnt[dst[e]], 1);
}

__global__ void scan_blocks_kernel(const int* __restrict__ cnt, int* __restrict__ partial,
                                   int* __restrict__ bsums, int n) {
  __shared__ int buf[256];
  int tid = threadIdx.x;
  int i = blockIdx.x * 256 + tid;
  buf[tid] = (i < n) ? cnt[i] : 0;
  __syncthreads();
  #pragma unroll
  for (int off = 1; off < 256; off <<= 1) {
    int t = (tid >= off) ? buf[tid - off] : 0;
    __syncthreads();
    buf[tid] += t;
    __syncthreads();
  }
  if (i < n) partial[i] = buf[tid];
  if (tid == 255) bsums[blockIdx.x] = buf[255];
}

__global__ void scan_sums_kernel(int* __restrict__ bsums, int nblk) {
  __shared__ int buf[256];
  int tid = threadIdx.x;
  buf[tid] = (tid < nblk) ? bsums[tid] : 0;
  __syncthreads();
  #pragma unroll
  for (int off = 1; off < 256; off <<= 1) {
    int t = (tid >= off) ? buf[tid - off] : 0;
    __syncthreads();
    buf[tid] += t;
    __syncthreads();
  }
  if (tid < nblk) bsums[tid] = buf[tid];
}

__global__ void scan_write_kernel(const int* __restrict__ partial, const int* __restrict__ bsums,
                                  int* __restrict__ rowp, int n) {
  int i = blockIdx.x * 256 + threadIdx.x;
  if (i < n) {
    int b = blockIdx.x;
    int off = (b > 0) ? bsums[b - 1] : 0;
    rowp[i + 1] = partial[i] + off;
    if (i == 0) rowp[0] = 0;
  }
}

__global__ void fill_self_kernel(const int* __restrict__ rowp, int* __restrict__ col,
                                 int* __restrict__ fillpos) {
  int i = blockIdx.x * 256 + threadIdx.x;
  if (i < N_NODES) {
    int p = rowp[i];
    col[p] = i;
    fillpos[i] = p + 1;
  }
}

__global__ void fill_edges_kernel(const int* __restrict__ src, const int* __restrict__ dst,
                                  int* __restrict__ fillpos, int* __restrict__ col) {
  int e = blockIdx.x * 256 + threadIdx.x;
  if (e < N_EDGES) {
    int d = dst[e];
    int p = atomicAdd(&fillpos[d], 1);
    col[p] = src[e];
  }
}

// ---------------- MFMA GEMM tiles (128-tile kernels: proj & gate) ----------------
#define GTM 128
#define GTK 64
#define LDB 72
#define SSTR 132

// input projection: out_bf[M,256] = A[M,K]@W^T + bias (bf16 out, staged coalesced)
__global__ __launch_bounds__(256) void gemm_proj_kernel(
    const u16* __restrict__ A, const u16* __restrict__ W,
    const float* __restrict__ bias, u16* __restrict__ outbf, int M, int K)
{
  __shared__ u16 smem[2 * GTM * LDB];
  u16* As = smem;
  u16* Bs = smem + GTM * LDB;
  int tid = threadIdx.x;
  int lane = tid & 63;
  int wave = tid >> 6;
  int wm = (wave >> 1) * 64;
  int wn = (wave & 1) * 64;
  int bm = blockIdx.y * GTM;
  int n0 = blockIdx.x * 128;
  int lr = tid >> 3;
  int lc = (tid & 7) * 8;

  floatx4 zero4 = {0.f, 0.f, 0.f, 0.f};
  floatx4 acc[4][4];
  #pragma unroll
  for (int i = 0; i < 4; i++)
    #pragma unroll
    for (int j = 0; j < 4; j++) acc[i][j] = zero4;

  int q8 = (lane >> 4) * 8;
  int mrow = lane & 15;

  for (int k0 = 0; k0 < K; k0 += GTK) {
    __syncthreads();
    #pragma unroll
    for (int p = 0; p < 4; p++) {
      int row = lr + p * 32;
      int gr = bm + row;
      short8 av = {0, 0, 0, 0, 0, 0, 0, 0};
      if (gr < M) av = *(const short8*)&A[(size_t)gr * K + k0 + lc];
      *(short8*)&As[row * LDB + lc] = av;
      short8 bv = *(const short8*)&W[(size_t)(n0 + row) * K + k0 + lc];
      *(short8*)&Bs[row * LDB + lc] = bv;
    }
    __syncthreads();
    #pragma unroll
    for (int h = 0; h < 2; h++) {
      short8 af[4], bf[4];
      #pragma unroll
      for (int i = 0; i < 4; i++)
        af[i] = *(const short8*)&As[(wm + i * 16 + mrow) * LDB + h * 32 + q8];
      #pragma unroll
      for (int j = 0; j < 4; j++)
        bf[j] = *(const short8*)&Bs[(wn + j * 16 + mrow) * LDB + h * 32 + q8];
      #pragma unroll
      for (int i = 0; i < 4; i++)
        #pragma unroll
        for (int j = 0; j < 4; j++)
          acc[i][j] = __builtin_amdgcn_mfma_f32_16x16x32_bf16(af[i], bf[j], acc[i][j], 0, 0, 0);
    }
  }

  __syncthreads();
  u16* stage = smem;
  int ccol = lane & 15;
  int crow4 = (lane >> 4) * 4;
  #pragma unroll
  for (int j = 0; j < 4; j++) {
    float bv = bias[n0 + wn + j * 16 + ccol];
    #pragma unroll
    for (int i = 0; i < 4; i++) {
      #pragma unroll
      for (int r = 0; r < 4; r++) {
        int row = wm + i * 16 + crow4 + r;
        stage[row * SSTR + wn + j * 16 + ccol] = f2b(acc[i][j][r] + bv);
      }
    }
  }
  __syncthreads();
  int rr = tid >> 1;
  int c0 = (tid & 1) * 64;
  int grow = bm + rr;
  if (grow < M) {
    const ushort4* sp = (const ushort4*)&stage[rr * SSTR + c0];
    ushort4* gp = (ushort4*)&outbf[(size_t)grow * H + n0 + c0];
    #pragma unroll
    for (int q = 0; q < 16; q++) gp[q] = sp[q];
  }
}

// ---------------- dual GEMM v2: A-resident in LDS, 64-row m-tiles ----------------
#define DTM 64
#define AST 264   // A stride in u16 (row step = 4 banks -> only 2-way alias, free)
#define SSTR2 132

__global__ __launch_bounds__(256) void gemm_dual2_kernel(
    const u16* __restrict__ A, const u16* __restrict__ Wlb, const u16* __restrict__ Wrb,
    const float* __restrict__ biasL, const float* __restrict__ biasR,
    u16* __restrict__ outL, u16* __restrict__ outR, int M)
{
  __shared__ u16 As[DTM * AST];      // 33.8 KB
  __shared__ u16 Bs[128 * LDB];      // 18.4 KB (also reused as epilogue stage)
  int tid = threadIdx.x;
  int lane = tid & 63;
  int wave = tid >> 6;
  int wn = wave * 32;
  int bm = blockIdx.x * DTM;
  int mrow = lane & 15;
  int q8 = (lane >> 4) * 8;
  int ccol = lane & 15;
  int crow4 = (lane >> 4) * 4;

  // stage full-K A tile once: 64 rows x 256 cols
  {
    int col = (tid & 31) * 8;
    int r0 = tid >> 5;
    #pragma unroll
    for (int it = 0; it < 8; it++) {
      int row = r0 + it * 8;
      int gr = bm + row;
      short8 av = {0, 0, 0, 0, 0, 0, 0, 0};
      if (gr < M) av = *(const short8*)&A[(size_t)gr * H + col];
      *(short8*)&As[row * AST + col] = av;
    }
  }

  floatx4 zero4 = {0.f, 0.f, 0.f, 0.f};

  for (int nt = 0; nt < 4; nt++) {
    const u16* W = (nt < 2) ? Wlb : Wrb;
    const float* bias = (nt < 2) ? biasL : biasR;
    u16* outp = (nt < 2) ? outL : outR;
    int n0 = (nt & 1) * 128;

    floatx4 acc[4][2];
    #pragma unroll
    for (int i = 0; i < 4; i++) {
      acc[i][0] = zero4;
      acc[i][1] = zero4;
    }

    for (int k0 = 0; k0 < H; k0 += 64) {
      __syncthreads();  // protects Bs vs prior reads (and A staging on first pass)
      {
        int col = (tid & 7) * 8;
        int r0 = tid >> 3;
        #pragma unroll
        for (int p2 = 0; p2 < 4; p2++) {
          int row = r0 + p2 * 32;
          short8 bv = *(const short8*)&W[(size_t)(n0 + row) * H + k0 + col];
          *(short8*)&Bs[row * LDB + col] = bv;
        }
      }
      __syncthreads();
      #pragma unroll
      for (int h = 0; h < 2; h++) {
        short8 af[4], bf[2];
        #pragma unroll
        for (int i = 0; i < 4; i++)
          af[i] = *(const short8*)&As[(i * 16 + mrow) * AST + k0 + h * 32 + q8];
        #pragma unroll
        for (int j = 0; j < 2; j++)
          bf[j] = *(const short8*)&Bs[(wn + j * 16 + mrow) * LDB + h * 32 + q8];
        #pragma unroll
        for (int i = 0; i < 4; i++)
          #pragma unroll
          for (int j = 0; j < 2; j++)
            acc[i][j] = __builtin_amdgcn_mfma_f32_16x16x32_bf16(af[i], bf[j], acc[i][j], 0, 0, 0);
      }
    }

    // staged coalesced epilogue (reuse Bs)
    __syncthreads();
    u16* stage = Bs;
    #pragma unroll
    for (int j = 0; j < 2; j++) {
      float bv = bias[n0 + wn + j * 16 + ccol];
      #pragma unroll
      for (int i = 0; i < 4; i++) {
        #pragma unroll
        for (int r = 0; r < 4; r++) {
          int row = i * 16 + crow4 + r;
          stage[row * SSTR2 + wn + j * 16 + ccol] = f2b(acc[i][j][r] + bv);
        }
      }
    }
    __syncthreads();
    {
      int row = tid >> 2;
      int c0 = (tid & 3) * 32;
      int grow = bm + row;
      if (grow < M) {
        #pragma unroll
        for (int q = 0; q < 8; q++)
          *(ushort4*)&outp[(size_t)grow * H + n0 + c0 + q * 4] =
              *(const ushort4*)&stage[row * SSTR2 + c0 + q * 4];
      }
    }
  }
}

// gate GEMM: gate[row] += sum_col relu(x@Wg1 + bg1)[col] * Wg2[col]; gate pre-init to bg2
__global__ __launch_bounds__(256) void gemm_gate_kernel(
    const u16* __restrict__ A, const u16* __restrict__ W,
    const float* __restrict__ bias, const float* __restrict__ Wg2,
    float* __restrict__ gate, int M)
{
  __shared__ u16 smem[2 * GTM * LDB];
  u16* As = smem;
  u16* Bs = smem + GTM * LDB;
  int tid = threadIdx.x;
  int lane = tid & 63;
  int wave = tid >> 6;
  int wm = (wave >> 1) * 64;
  int wn = (wave & 1) * 64;
  int bm = blockIdx.y * GTM;
  int bn = blockIdx.x * 128;
  int lr = tid >> 3;
  int lc = (tid & 7) * 8;

  floatx4 zero4 = {0.f, 0.f, 0.f, 0.f};
  floatx4 acc[4][4];
  #pragma unroll
  for (int i = 0; i < 4; i++)
    #pragma unroll
    for (int j = 0; j < 4; j++) acc[i][j] = zero4;

  int q8 = (lane >> 4) * 8;
  int mrow = lane & 15;

  for (int k0 = 0; k0 < H; k0 += GTK) {
    __syncthreads();
    #pragma unroll
    for (int p = 0; p < 4; p++) {
      int row = lr + p * 32;
      int gr = bm + row;
      short8 av = {0, 0, 0, 0, 0, 0, 0, 0};
      if (gr < M) av = *(const short8*)&A[(size_t)gr * H + k0 + lc];
      *(short8*)&As[row * LDB + lc] = av;
      short8 bv = *(const short8*)&W[(size_t)(bn + row) * H + k0 + lc];
      *(short8*)&Bs[row * LDB + lc] = bv;
    }
    __syncthreads();
    #pragma unroll
    for (int h = 0; h < 2; h++) {
      short8 af[4], bf[4];
      #pragma unroll
      for (int i = 0; i < 4; i++)
        af[i] = *(const short8*)&As[(wm + i * 16 + mrow) * LDB + h * 32 + q8];
      #pragma unroll
      for (int j = 0; j < 4; j++)
        bf[j] = *(const short8*)&Bs[(wn + j * 16 + mrow) * LDB + h * 32 + q8];
      #pragma unroll
      for (int i = 0; i < 4; i++)
        #pragma unroll
        for (int j = 0; j < 4; j++)
          acc[i][j] = __builtin_amdgcn_mfma_f32_16x16x32_bf16(af[i], bf[j], acc[i][j], 0, 0, 0);
    }
  }

  int ccol = lane & 15;
  float bv[4], wv[4];
  #pragma unroll
  for (int j = 0; j < 4; j++) {
    int col = bn + wn + j * 16 + ccol;
    bv[j] = bias[col];
    wv[j] = Wg2[col];
  }
  #pragma unroll
  for (int i = 0; i < 4; i++) {
    #pragma unroll
    for (int r = 0; r < 4; r++) {
      float p = 0.f;
      #pragma unroll
      for (int j = 0; j < 4; j++) {
        float hcol = fmaxf(acc[i][j][r] + bv[j], 0.f);
        p += hcol * wv[j];
      }
      p += __shfl_xor(p, 1, 64);
      p += __shfl_xor(p, 2, 64);
      p += __shfl_xor(p, 4, 64);
      p += __shfl_xor(p, 8, 64);
      int row = bm + wm + i * 16 + (lane >> 4) * 4 + r;
      if ((lane & 15) == 0 && row < M) atomicAdd(&gate[row], p);
    }
  }
}

// ---------------- fused edge softmax + aggregate + LN + residual (unroll-2, branch-free) ----------------
__global__ __launch_bounds__(256) void layer_fused_kernel(
    const u16* __restrict__ xl, const u16* __restrict__ xr,
    u16* __restrict__ xbf,
    const int* __restrict__ rowp, const int* __restrict__ col,
    const float* __restrict__ att, const float* __restrict__ bias_c,
    const float* __restrict__ ln_g, const float* __restrict__ ln_b)
{
  int lane = threadIdx.x & 63;
  int v = blockIdx.x * 4 + (threadIdx.x >> 6);
  if (v >= N_NODES) return;
  int f4 = lane << 2;
  size_t rowbase = (size_t)v * H;
  ushort4 xr4 = *(const ushort4*)&xr[rowbase + f4];
  float xrx = b2f(xr4.x), xry = b2f(xr4.y), xrz = b2f(xr4.z), xrw = b2f(xr4.w);
  float4 attv = *(const float4*)&att[f4];
  int beg = rowp[v], end = rowp[v + 1];
  float m = -INFINITY, d = 0.f;
  float ox = 0.f, oy = 0.f, oz = 0.f, ow = 0.f;
  int p = beg;
  for (; p + 2 <= end; p += 2) {
    int u0 = col[p];
    int u1 = col[p + 1];
    ushort4 a04 = *(const ushort4*)&xl[(size_t)u0 * H + f4];
    ushort4 a14 = *(const ushort4*)&xl[(size_t)u1 * H + f4];
    float a0x = b2f(a04.x), a0y = b2f(a04.y), a0z = b2f(a04.z), a0w = b2f(a04.w);
    float a1x = b2f(a14.x), a1y = b2f(a14.y), a1z = b2f(a14.z), a1w = b2f(a14.w);
    float t0x = a0x + xrx; t0x = t0x > 0.f ? t0x : NEG_SLOPE * t0x;
    float t0y = a0y + xry; t0y = t0y > 0.f ? t0y : NEG_SLOPE * t0y;
    float t0z = a0z + xrz; t0z = t0z > 0.f ? t0z : NEG_SLOPE * t0z;
    float t0w = a0w + xrw; t0w = t0w > 0.f ? t0w : NEG_SLOPE * t0w;
    float t1x = a1x + xrx; t1x = t1x > 0.f ? t1x : NEG_SLOPE * t1x;
    float t1y = a1y + xry; t1y = t1y > 0.f ? t1y : NEG_SLOPE * t1y;
    float t1z = a1z + xrz; t1z = t1z > 0.f ? t1z : NEG_SLOPE * t1z;
    float t1w = a1w + xrw; t1w = t1w > 0.f ? t1w : NEG_SLOPE * t1w;
    float pe0 = t0x * attv.x + t0y * attv.y + t0z * attv.z + t0w * attv.w;
    float pe1 = t1x * attv.x + t1y * attv.y + t1z * attv.z + t1w * attv.w;
    #pragma unroll
    for (int off = 32; off > 0; off >>= 1) {
      pe0 += __shfl_xor(pe0, off, 64);
      pe1 += __shfl_xor(pe1, off, 64);
    }
    float mn = fmaxf(m, fmaxf(pe0, pe1));
    float sc = __expf(m - mn);
    float w0 = __expf(pe0 - mn);
    float w1 = __expf(pe1 - mn);
    d = fmaf(d, sc, w0 + w1);
    ox = fmaf(ox, sc, fmaf(w0, a0x, w1 * a1x));
    oy = fmaf(oy, sc, fmaf(w0, a0y, w1 * a1y));
    oz = fmaf(oz, sc, fmaf(w0, a0z, w1 * a1z));
    ow = fmaf(ow, sc, fmaf(w0, a0w, w1 * a1w));
    m = mn;
  }
  if (p < end) {
    int u0 = col[p];
    ushort4 a04 = *(const ushort4*)&xl[(size_t)u0 * H + f4];
    float a0x = b2f(a04.x), a0y = b2f(a04.y), a0z = b2f(a04.z), a0w = b2f(a04.w);
    float t0x = a0x + xrx; t0x = t0x > 0.f ? t0x : NEG_SLOPE * t0x;
    float t0y = a0y + xry; t0y = t0y > 0.f ? t0y : NEG_SLOPE * t0y;
    float t0z = a0z + xrz; t0z = t0z > 0.f ? t0z : NEG_SLOPE * t0z;
    float t0w = a0w + xrw; t0w = t0w > 0.f ? t0w : NEG_SLOPE * t0w;
    float pe0 = t0x * attv.x + t0y * attv.y + t0z * attv.z + t0w * attv.w;
    pe0 = wave_reduce_sum(pe0);
    float mn = fmaxf(m, pe0);
    float sc = __expf(m - mn);
    float w0 = __expf(pe0 - mn);
    d = fmaf(d, sc, w0);
    ox = fmaf(ox, sc, w0 * a0x);
    oy = fmaf(oy, sc, w0 * a0y);
    oz = fmaf(oz, sc, w0 * a0z);
    ow = fmaf(ow, sc, w0 * a0w);
    m = mn;
  }
  float invd = 1.0f / d;
  float4 bc4 = *(const float4*)&bias_c[f4];
  ox = ox * invd + bc4.x;
  oy = oy * invd + bc4.y;
  oz = oz * invd + bc4.z;
  ow = ow * invd + bc4.w;
  float s = wave_reduce_sum(ox + oy + oz + ow);
  float mean = s * (1.0f / H);
  float cx = ox - mean, cy = oy - mean, cz = oz - mean, cw = ow - mean;
  float sq = wave_reduce_sum(cx * cx + cy * cy + cz * cz + cw * cw);
  float rstd = rsqrtf(sq * (1.0f / H) + LN_EPS);
  float4 g4 = *(const float4*)&ln_g[f4];
  float4 b4 = *(const float4*)&ln_b[f4];
  ushort4 xres4 = *(const ushort4*)&xbf[rowbase + f4];
  float yx = fmaxf(cx * rstd * g4.x + b4.x, 0.f) + b2f(xres4.x);
  float yy = fmaxf(cy * rstd * g4.y + b4.y, 0.f) + b2f(xres4.y);
  float yz = fmaxf(cz * rstd * g4.z + b4.z, 0.f) + b2f(xres4.z);
  float yw = fmaxf(cw * rstd * g4.w + b4.w, 0.f) + b2f(xres4.w);
  ushort4 yb;
  yb.x = f2b(yx); yb.y = f2b(yy); yb.z = f2b(yz); yb.w = f2b(yw);
  *(ushort4*)&xbf[rowbase + f4] = yb;
}

// ---------------- gate init (+ graph-bounds defaults) ----------------
__global__ void gate_init_kernel(float* __restrict__ gate, const float* __restrict__ bg2,
                                 int* __restrict__ gstart, int* __restrict__ gend) {
  int i = blockIdx.x * 256 + threadIdx.x;
  if (i < N_NODES) gate[i] = bg2[0];
  if (i < NGRAPH) { gstart[i] = 0; gend[i] = 0; }
}

// ---------------- graph bounds (sorted batch) ----------------
__global__ void gbounds_kernel(const int* __restrict__ batch, int* __restrict__ gstart,
                               int* __restrict__ gend) {
  int i = blockIdx.x * 256 + threadIdx.x;
  if (i < N_NODES) {
    int b = batch[i];
    if (i == 0 || batch[i - 1] != b) gstart[b] = i;
    if (i == N_NODES - 1 || batch[i + 1] != b) gend[b] = i + 1;
  }
}

// ---------------- pooling: per-graph softmax stats (+ pooled zero) ----------------
__global__ __launch_bounds__(256) void pool_prep_kernel(
    const float* __restrict__ gate, const int* __restrict__ gstart,
    const int* __restrict__ gend, float* __restrict__ gmax, float* __restrict__ gdinv,
    float* __restrict__ pooled)
{
  __shared__ float red[256];
  int g = blockIdx.x, tid = threadIdx.x;
  pooled[(size_t)g * H + tid] = 0.f;
  int s = gstart[g], e = gend[g];
  float lm = -INFINITY;
  for (int i = s + tid; i < e; i += 256) lm = fmaxf(lm, gate[i]);
  red[tid] = lm;
  __syncthreads();
  for (int off = 128; off; off >>= 1) {
    if (tid < off) red[tid] = fmaxf(red[tid], red[tid + off]);
    __syncthreads();
  }
  float m = red[0];
  __syncthreads();
  float lsum = 0.0f;
  for (int i = s + tid; i < e; i += 256) lsum += __expf(gate[i] - m);
  red[tid] = lsum;
  __syncthreads();
  for (int off = 128; off; off >>= 1) {
    if (tid < off) red[tid] += red[tid + off];
    __syncthreads();
  }
  if (tid == 0) {
    gmax[g] = m;
    gdinv[g] = (s < e) ? 1.0f / red[0] : 0.0f;
  }
}

// ---------------- pooling: weighted accumulate (128 nodes per block, bf16 x) ----------------
__global__ __launch_bounds__(256) void pool_accum_kernel(
    const float* __restrict__ gate, const u16* __restrict__ xbf,
    const int* __restrict__ batch, const float* __restrict__ gmax,
    const float* __restrict__ gdinv, float* __restrict__ pooled)
{
  __shared__ float wl[128];
  __shared__ int gl[128];
  int b0 = blockIdx.x * 128;
  int tid = threadIdx.x;
  if (tid < 128) {
    int v = b0 + tid;
    if (v < N_NODES) {
      int g = batch[v];
      gl[tid] = g;
      wl[tid] = __expf(gate[v] - gmax[g]) * gdinv[g];
    } else {
      gl[tid] = -1;
      wl[tid] = 0.f;
    }
  }
  __syncthreads();
  int cnt = min(128, N_NODES - b0);
  float acc = 0.f;
  int cur = gl[0];
  for (int j = 0; j < cnt; j++) {
    int g = gl[j];
    if (g != cur) {
      atomicAdd(&pooled[(size_t)cur * H + tid], acc);
      acc = 0.f;
      cur = g;
    }
    acc += wl[j] * b2f(xbf[(size_t)(b0 + j) * H + tid]);
  }
  if (cur >= 0) atomicAdd(&pooled[(size_t)cur * H + tid], acc);
}

// ---------------- fused head: pooled -> z -> {cls, r1} -> residual (one launch) ----------------
__global__ __launch_bounds__(256) void head_kernel(
    const float* __restrict__ pooled,
    const float* __restrict__ Ws, const float* __restrict__ bs,
    const float* __restrict__ Wc, const float* __restrict__ bc,
    const float* __restrict__ Wr1, const float* __restrict__ br1,
    const float* __restrict__ Wr2, const float* __restrict__ br2,
    float* __restrict__ out)
{
  __shared__ float psh[256];
  __shared__ float zsh[256];
  __shared__ float r1sh[128];
  int g = blockIdx.x, tid = threadIdx.x;
  psh[tid] = pooled[(size_t)g * H + tid];
  __syncthreads();
  {
    float acc = bs[tid];
    const float4* wr = (const float4*)&Ws[(size_t)tid * H];
    for (int k4 = 0; k4 < H / 4; k4++) {
      float4 wv = wr[k4];
      float4 av = *(const float4*)&psh[k4 * 4];
      acc += av.x * wv.x + av.y * wv.y + av.z * wv.z + av.w * wv.w;
    }
    zsh[tid] = fmaxf(acc, 0.f);
  }
  __syncthreads();
  if (tid < NB) {
    float acc = bc[tid];
    const float4* wr = (const float4*)&Wc[(size_t)tid * H];
    for (int k4 = 0; k4 < H / 4; k4++) {
      float4 wv = wr[k4];
      float4 av = *(const float4*)&zsh[k4 * 4];
      acc += av.x * wv.x + av.y * wv.y + av.z * wv.z + av.w * wv.w;
    }
    out[(size_t)g * NB + tid] = acc;
  }
  if (tid < 128) {
    float acc = br1[tid];
    const float4* wr = (const float4*)&Wr1[(size_t)tid * H];
    for (int k4 = 0; k4 < H / 4; k4++) {
      float4 wv = wr[k4];
      float4 av = *(const float4*)&zsh[k4 * 4];
      acc += av.x * wv.x + av.y * wv.y + av.z * wv.z + av.w * wv.w;
    }
    r1sh[tid] = fmaxf(acc, 0.f);
  }
  __syncthreads();
  if (tid < 64) {
    float s2 = r1sh[tid] * Wr2[tid] + r1sh[tid + 64] * Wr2[tid + 64];
    s2 = wave_reduce_sum(s2);
    if (tid == 0) out[(size_t)NGRAPH * NB + g] = tanhf(s2 + br2[0]);
  }
}

// ---------------- launcher ----------------
extern "C" void kernel_launch(void* const* d_in, const int* in_sizes, int n_in,
                              void* d_out, int out_size, void* d_ws, size_t ws_size,
                              hipStream_t stream) {
  const float* x_in   = (const float*)d_in[0];
  const int*   eidx   = (const int*)d_in[1];
  const int*   batch  = (const int*)d_in[2];
  const float* W_in   = (const float*)d_in[3];
  const float* b_in   = (const float*)d_in[4];
  const float* Wl     = (const float*)d_in[5];
  const float* bl     = (const float*)d_in[6];
  const float* Wr     = (const float*)d_in[7];
  const float* br     = (const float*)d_in[8];
  const float* att    = (const float*)d_in[9];
  const float* bias_c = (const float*)d_in[10];
  const float* ln_g   = (const float*)d_in[11];
  const float* ln_b   = (const float*)d_in[12];
  const float* Wg1    = (const float*)d_in[13];
  const float* bg1    = (const float*)d_in[14];
  const float* Wg2    = (const float*)d_in[15];
  const float* bg2    = (const float*)d_in[16];
  const float* Ws     = (const float*)d_in[17];
  const float* bs     = (const float*)d_in[18];
  const float* Wc     = (const float*)d_in[19];
  const float* bc     = (const float*)d_in[20];
  const float* Wr1    = (const float*)d_in[21];
  const float* br1    = (const float*)d_in[22];
  const float* Wr2    = (const float*)d_in[23];
  const float* br2    = (const float*)d_in[24];
  float* out = (float*)d_out;

  char* w = (char*)d_ws;
  u16* x_bf   = (u16*)w;    w += sizeof(u16) * (size_t)N_NODES * H;
  u16* xl_bf  = (u16*)w;    w += sizeof(u16) * (size_t)N_NODES * H;
  u16* xr_bf  = (u16*)w;    w += sizeof(u16) * (size_t)N_NODES * H;
  u16* xin_bf = (u16*)w;    w += sizeof(u16) * (size_t)N_NODES * IN_DIM;
  u16* win_bf = (u16*)w;    w += sizeof(u16) * (size_t)H * IN_DIM;
  u16* wl_bf  = (u16*)w;    w += sizeof(u16) * (size_t)LAYERS * H * H;
  u16* wr_bf  = (u16*)w;    w += sizeof(u16) * (size_t)LAYERS * H * H;
  u16* wg1_bf = (u16*)w;    w += sizeof(u16) * (size_t)H * H;
  float* pooled = (float*)w; w += sizeof(float) * NGRAPH * H;
  float* gate = (float*)w;  w += sizeof(float) * N_NODES;
  float* gmax = (float*)w;  w += sizeof(float) * NGRAPH;
  float* gdinv= (float*)w;  w += sizeof(float) * NGRAPH;
  int* cnt    = (int*)w;    w += sizeof(int) * N_NODES;
  int* rowp   = (int*)w;    w += sizeof(int) * (N_NODES + 1);
  int* col    = (int*)w;    w += sizeof(int) * EE;
  int* partial= (int*)w;    w += sizeof(int) * N_NODES;
  int* bsums  = (int*)w;    w += sizeof(int) * 256;
  int* gstart = (int*)w;    w += sizeof(int) * NGRAPH;
  int* gend   = (int*)w;    w += sizeof(int) * NGRAPH;
  (void)ws_size; (void)n_in; (void)in_sizes; (void)out_size;

  const int* src = eidx;
  const int* dst = eidx + N_EDGES;
  int nblkN = (N_NODES + 255) / 256;
  int nblkE = (N_EDGES + 255) / 256;
  int mtiles = (N_NODES + GTM - 1) / GTM;
  int mtiles2 = (N_NODES + DTM - 1) / DTM;

  // CSR build (by dst, self-loops included)
  init_counts_kernel<<<nblkN, 256, 0, stream>>>(cnt);
  count_edges_kernel<<<nblkE, 256, 0, stream>>>(dst, cnt);
  scan_blocks_kernel<<<nblkN, 256, 0, stream>>>(cnt, partial, bsums, N_NODES);
  scan_sums_kernel<<<1, 256, 0, stream>>>(bsums, nblkN);
  scan_write_kernel<<<nblkN, 256, 0, stream>>>(partial, bsums, rowp, N_NODES);
  fill_self_kernel<<<nblkN, 256, 0, stream>>>(rowp, col, cnt);
  fill_edges_kernel<<<nblkE, 256, 0, stream>>>(src, dst, cnt, col);

  // casts: all weights in one launch; x_in separate
  {
    int maxn4 = LAYERS * H * H / 4;
    dim3 gcast((maxn4 + 255) / 256, 4);
    cast_weights_kernel<<<gcast, 256, 0, stream>>>(W_in, Wg1, Wl, Wr,
                                                   win_bf, wg1_bf, wl_bf, wr_bf);
    int n4 = N_NODES * IN_DIM / 4;
    cast_bf16_kernel<<<(n4 + 255) / 256, 256, 0, stream>>>(x_in, xin_bf, n4);
  }

  // input projection -> x_bf
  dim3 gproj(2, mtiles);
  gemm_proj_kernel<<<gproj, 256, 0, stream>>>(xin_bf, win_bf, b_in, x_bf, N_NODES, IN_DIM);

  int nblkV = N_NODES / 4;
  for (int l = 0; l < LAYERS; l++) {
    gemm_dual2_kernel<<<mtiles2, 256, 0, stream>>>(x_bf,
        wl_bf + (size_t)l * H * H, wr_bf + (size_t)l * H * H,
        bl + l * H, br + l * H, xl_bf, xr_bf, N_NODES);
    layer_fused_kernel<<<nblkV, 256, 0, stream>>>(xl_bf, xr_bf, x_bf, rowp, col,
        att + l * H, bias_c + l * H, ln_g + l * H, ln_b + l * H);
  }

  // gate (fused GEMM + row-dot)
  gate_init_kernel<<<nblkN, 256, 0, stream>>>(gate, bg2, gstart, gend);
  dim3 ggate(2, mtiles);
  gemm_gate_kernel<<<ggate, 256, 0, stream>>>(x_bf, wg1_bf, bg1, Wg2, gate, N_NODES);

  // pooling
  gbounds_kernel<<<nblkN, 256, 0, stream>>>(batch, gstart, gend);
  pool_prep_kernel<<<NGRAPH, 256, 0, stream>>>(gate, gstart, gend, gmax, gdinv, pooled);
  pool_accum_kernel<<<(N_NODES + 127) / 128, 256, 0, stream>>>(gate, x_bf, batch, gmax, gdinv, pooled);

  // fused heads
  head_kernel<<<NGRAPH, 256, 0, stream>>>(pooled, Ws, bs, Wc, bc, Wr1, br1, Wr2, br2, out);
}